// Round 5
// baseline (223.172 us; speedup 1.0000x reference)
//
#include <hip/hip_runtime.h>
#include <hip/hip_bf16.h>
#include <math.h>

#define HW 3136
#define NPOS 50176          // 16 images x 3136
#define NC 192
#define NHEADS 6
#define IMG 56
#define NATT 486
#define ATT_SCALE 0.17677669529663687f  // 32^-0.5

typedef __attribute__((ext_vector_type(8))) short short8;
typedef __attribute__((ext_vector_type(8))) unsigned short ushort8;
typedef __attribute__((ext_vector_type(4))) float float4v;
typedef __attribute__((ext_vector_type(4))) unsigned int uint4v;

__device__ __forceinline__ float bf2f(unsigned short u) {
    unsigned int x = ((unsigned int)u) << 16;
    return __builtin_bit_cast(float, x);
}
__device__ __forceinline__ float bf2f_lo(unsigned int u) {
    return __builtin_bit_cast(float, u << 16);
}
__device__ __forceinline__ float bf2f_hi(unsigned int u) {
    return __builtin_bit_cast(float, u & 0xffff0000u);
}
__device__ __forceinline__ unsigned short f2bf(float f) {
    __hip_bfloat16 h = __float2bfloat16(f);
    return __builtin_bit_cast(unsigned short, h);
}

// x [16][192][3136] fp32 -> xt [50176][192] bf16 (channels-last). grid (784,3), block 256.
__global__ __launch_bounds__(256) void transpose_x(const float* __restrict__ x,
                                                   unsigned short* __restrict__ xt)
{
    __shared__ float tile[64][65];
    int bx = blockIdx.x;
    int n = (bx * 64) / HW;
    int hw0 = (bx * 64) % HW;
    int c0 = blockIdx.y * 64;
    int tl = threadIdx.x & 63, tg = threadIdx.x >> 6;
    const float* xn = x + (size_t)n * NC * HW;
#pragma unroll
    for (int i = 0; i < 16; ++i)
        tile[tg * 16 + i][tl] = xn[(size_t)(c0 + tg * 16 + i) * HW + hw0 + tl];
    __syncthreads();
    unsigned short* xp = xt + ((size_t)n * HW + hw0) * NC + c0;
#pragma unroll
    for (int i = 0; i < 16; ++i) {
        int hwr = tg * 16 + i;
        xp[(size_t)hwr * NC + tl] = f2bf(tile[tl][hwr]);
    }
}

// Weight prep: Wall[768][192] = [Wv^T ; Wa^T permuted, stride 10], ball[768],
// Wpt[192][192] = Wp^T. grid 576, block 256.
__global__ __launch_bounds__(256) void prep_weights(
    const float* __restrict__ Wv, const float* __restrict__ Wa, const float* __restrict__ Wp,
    const float* __restrict__ ba,
    unsigned short* __restrict__ Wall, unsigned short* __restrict__ Wpt,
    float* __restrict__ ball)
{
    int idx = blockIdx.x * 256 + threadIdx.x;
    if (idx < 36864) {
        int d = idx / 192, k = idx - d * 192;
        Wpt[idx] = f2bf(Wp[(size_t)k * NC + d]);
    }
    if (idx < 147456) {                       // 768*192
        int d = idx / 192, k = idx - d * 192;
        unsigned short val;
        float bv = 0.f;
        if (d < 192) {
            val = f2bf(Wv[(size_t)k * NC + d]);
        } else {
            int dp = d - 192;                 // 0..575
            int head = dp / 96, rr = dp - head * 96;
            int k9 = rr / 10, l = rr - k9 * 10;
            bool valid = (k9 < 9) && (l < 9);
            int src = head * 81 + k9 * 9 + l;
            val = valid ? f2bf(Wa[(size_t)k * NATT + src]) : (unsigned short)0;
            bv = valid ? ba[src] : 0.f;
        }
        Wall[idx] = val;
        if (k == 0) ball[d] = bv;
    }
}

// GEMM over all 768 output cols; epilogue scatters into fused-friendly layouts:
//   cols [0,192)   -> V[head][pos][32]           (64-B records)
//   cols [192,768) -> AT[head*9+k9][pos][10]     (20-B records; k9==9 pads dropped)
// v9: LDS-free register GEMM. Inputs are L2/L3-warm (produced by prior kernels),
// so staging solved nothing and cost 2 barriers + conflicted ds_reads per step.
// Fragments load straight from global: one wave-load = 16 fully-consumed 64-B
// lines ((row)*384 + s*64 + fq*16; fq 0..3 tile a full line). No barriers at
// all -> compiler freely pipelines the 6 K-steps; no LDS -> reg-only occupancy.
// XCD row-grouping kept: all 6 col-blocks of row-tile r on XCD r%8.
// grid 2352 (1-D), block 256.
__global__ __launch_bounds__(256) void gemm_big(
    const unsigned short* __restrict__ A, const unsigned short* __restrict__ W,
    const float* __restrict__ ball,
    unsigned short* __restrict__ Vo, unsigned short* __restrict__ ATo)
{
    int t = threadIdx.x, lane = t & 63, wave = t >> 6;
    int bi = blockIdx.x;
    int slot = bi >> 3;                // 0..293
    int q6 = slot / 6;
    int rr_ = (bi & 7) + 8 * q6;       // row-tile 0..391, xcd-grouped
    int cc_ = slot - 6 * q6;           // col-tile 0..5
    int col0 = cc_ * 128, row0 = rr_ * 128;
    int fr = lane & 15, fq = lane >> 4;
    int wm = (wave >> 1) * 64, wn = (wave & 1) * 64;

    const char* pA = (const char*)A + (size_t)(row0 + wm + fr) * 384 + fq * 16;
    const char* pB = (const char*)W + (size_t)(col0 + wn + fr) * 384 + fq * 16;

    float4v acc[4][4] = {};

#pragma unroll
    for (int s = 0; s < 6; ++s) {
        short8 af[4], bf[4];
#pragma unroll
        for (int mi = 0; mi < 4; ++mi)
            af[mi] = *(const short8*)(pA + mi * (16 * 384) + s * 64);
#pragma unroll
        for (int ni = 0; ni < 4; ++ni)
            bf[ni] = *(const short8*)(pB + ni * (16 * 384) + s * 64);
#pragma unroll
        for (int mi = 0; mi < 4; ++mi)
#pragma unroll
            for (int ni = 0; ni < 4; ++ni)
                acc[mi][ni] = __builtin_amdgcn_mfma_f32_16x16x32_bf16(
                    af[mi], bf[ni], acc[mi][ni], 0, 0, 0);
    }

#pragma unroll
    for (int ni = 0; ni < 4; ++ni) {
        int col = col0 + wn + ni * 16 + fr;
        float b = ball[col];
        unsigned short* bptr;
        size_t rstr;
        bool valid;
        if (col < 192) {
            int hd = col >> 5, ch = col & 31;
            bptr = Vo + ((size_t)hd * NPOS) * 32 + ch;
            rstr = 32;
            valid = true;
        } else {
            int dp = col - 192;
            int hd = dp / 96, rr = dp - hd * 96;
            int k9 = rr / 10, l = rr - k9 * 10;
            valid = (k9 < 9);
            bptr = ATo + ((size_t)(hd * 9 + (k9 < 9 ? k9 : 8)) * NPOS) * 10 + l;
            rstr = 10;
        }
#pragma unroll
        for (int mi = 0; mi < 4; ++mi) {
            int row = row0 + wm + mi * 16 + fq * 4;
#pragma unroll
            for (int r = 0; r < 4; ++r) {
                unsigned short val = f2bf(acc[mi][ni][r] + b);
                if (valid) bptr[(size_t)(row + r) * rstr] = val;
            }
        }
    }
}

// out[img][m][phw] = sum_k Wpt[m][k]*fold[n][k] + bias[m]; 64(m) x 256(n) tile.
// grid (196, 3), block 256, 4 waves each 64x64.
// v9: LDS-free register GEMM (same surgery as gemm_big; Wpt is 36 KB L1/L2-hot,
// fold rows are L2/L3-warm from fused_att_agg).
__global__ __launch_bounds__(256) void gemm_small(
    const unsigned short* __restrict__ A,   // Wpt [192][192]
    const unsigned short* __restrict__ B,   // fold [50176][192]
    const float* __restrict__ bias, float* __restrict__ out)
{
    int t = threadIdx.x, lane = t & 63, wave = t >> 6;
    int n0 = blockIdx.x * 256, m0 = blockIdx.y * 64;
    int fr = lane & 15, fq = lane >> 4;

    const char* pA = (const char*)A + (size_t)(m0 + fr) * 384 + fq * 16;
    const char* pB = (const char*)B + (size_t)(n0 + wave * 64 + fr) * 384 + fq * 16;

    float4v acc[4][4] = {};

#pragma unroll
    for (int s = 0; s < 6; ++s) {
        short8 af[4], bf[4];
#pragma unroll
        for (int mi = 0; mi < 4; ++mi)
            af[mi] = *(const short8*)(pA + mi * (16 * 384) + s * 64);
#pragma unroll
        for (int ni = 0; ni < 4; ++ni)
            bf[ni] = *(const short8*)(pB + ni * (16 * 384) + s * 64);
#pragma unroll
        for (int mi = 0; mi < 4; ++mi)
#pragma unroll
            for (int ni = 0; ni < 4; ++ni)
                acc[mi][ni] = __builtin_amdgcn_mfma_f32_16x16x32_bf16(
                    af[mi], bf[ni], acc[mi][ni], 0, 0, 0);
    }

#pragma unroll
    for (int ni = 0; ni < 4; ++ni) {
        int n = n0 + wave * 64 + ni * 16 + fr;
        int img = n / HW, phw = n - img * HW;
        float* op = out + (size_t)img * (NC * HW) + phw;
#pragma unroll
        for (int mi = 0; mi < 4; ++mi) {
            int m = m0 + mi * 16 + fq * 4;
#pragma unroll
            for (int r = 0; r < 4; ++r)
                op[(size_t)(m + r) * HW] = acc[mi][ni][r] + bias[m + r];
        }
    }
}

// Fused softmax + weight-combine + aggregation, v7: coalesced global layouts.
// Block = one head x (8x28) image tile (224 positions, 256 threads).
//  - V[head][pos][32]: halo staging reads are fully contiguous per wave.
//  - AT[head*9+k][pos][10]: softmax tap k reads consecutive pos across lanes.
//  - LDS: 4 q-planes, plane stride 434 chunks (16 B each; 434 mod 8 = 2 makes
//    the interleaved write mapping q=u&3 hit every bank-quad exactly 2x per
//    16-lane phase), row stride 36 chunks (read-balanced for the 28-wide map).
__global__ __launch_bounds__(256, 4) void fused_att_agg(
    const unsigned short* __restrict__ V, const unsigned short* __restrict__ AT,
    unsigned short* __restrict__ fold)
{
    __shared__ __align__(16) char vt[4 * 434 * 16];   // 27776 B
    int t = threadIdx.x;
    int bid = blockIdx.x;
    int head = bid % NHEADS; int tmp = bid / NHEADS;
    int tcol = tmp & 1; tmp >>= 1;
    int trow = tmp % 7; int img = tmp / 7;
    int h0 = trow * 8, w0 = tcol * 28;

    // ---- issue v-halo loads into registers (clamped addr + zero mask) ----
    const unsigned short* Vh = V + (size_t)head * NPOS * 32;
    ushort8 stg[6];
#pragma unroll
    for (int i = 0; i < 6; ++i) {
        int u = i * 256 + t;                 // 0..1535
        int slot = u >> 2, q = u & 3;        // slot = vrow*32+vcol, q = 16-B quarter
        int vrow = slot >> 5, vcol = slot & 31;
        int hh = h0 - 2 + vrow, ww = w0 - 2 + vcol;
        bool ok = (hh >= 0) & (hh < IMG) & (ww >= 0) & (ww < IMG);
        int hc = min(max(hh, 0), IMG - 1);
        int wcl = min(max(ww, 0), IMG - 1);
        ushort8 val = *(const ushort8*)(Vh + (size_t)(img * HW + hc * IMG + wcl) * 32 + q * 8);
        if (!ok) val = (ushort8){};
        stg[i] = val;
    }

    // ---- softmax -> 5x5 stencil weights, fully in registers ----
    int ph = t / 28, pw = t - (t / 28) * 28;
    int h = h0 + ph, w = w0 + pw;
    float wc[25];
#pragma unroll
    for (int d = 0; d < 25; ++d) wc[d] = 0.f;
    if (t < 224) {
        int head9 = head * 9;
#pragma unroll
        for (int k = 0; k < 9; ++k) {
            const int oky = k / 3 - 1, okx = k % 3 - 1;
            int hh = h - oky, ww = w - okx;
            bool ok = (hh >= 0) & (hh < IMG) & (ww >= 0) & (ww < IMG);
            int hc = min(max(hh, 0), IMG - 1);
            int wcl = min(max(ww, 0), IMG - 1);
            size_t nidx = (size_t)img * HW + hc * IMG + wcl;
            const unsigned int* ap32 =
                (const unsigned int*)(AT + ((size_t)(head9 + k) * NPOS + nidx) * 10);
            unsigned int u0 = ap32[0], u1 = ap32[1], u2 = ap32[2], u3 = ap32[3], u4 = ap32[4];
            float a[9] = { bf2f_lo(u0), bf2f_hi(u0), bf2f_lo(u1), bf2f_hi(u1),
                           bf2f_lo(u2), bf2f_hi(u2), bf2f_lo(u3), bf2f_hi(u3),
                           bf2f_lo(u4) };
            float m = -1e30f;
#pragma unroll
            for (int l = 0; l < 9; ++l) m = fmaxf(m, a[l]);
            float s = 0.f;
#pragma unroll
            for (int l = 0; l < 9; ++l) {
                a[l] = __expf((a[l] - m) * ATT_SCALE);
                s += a[l];
            }
            float g = ok ? (1.f / s) : 0.f;   // invalid neighbor contributes 0
#pragma unroll
            for (int l = 0; l < 9; ++l) {
                const int dy = (l / 3 - 1) - oky + 2;
                const int dx = (l % 3 - 1) - okx + 2;
                wc[dy * 5 + dx] += a[l] * g;
            }
        }
    }

    // ---- commit staged halo to LDS (write-balanced: plane stride 2 mod 8) ----
#pragma unroll
    for (int i = 0; i < 6; ++i) {
        int u = i * 256 + t;
        int slot = u >> 2, q = u & 3;
        int vrow = slot >> 5, vcol = slot & 31;
        *(ushort8*)(vt + q * (434 * 16) + (vrow * 36 + vcol) * 16) = stg[i];
    }
    __syncthreads();

    // ---- aggregate: 25 taps x 4 quarters, read-balanced, imm offsets ----
    if (t < 224) {
        int base = (ph * 36 + pw) * 16;
        int pos = img * HW + h * IMG + w;
        unsigned short* fo = fold + (size_t)pos * NC + head * 32;
#pragma unroll
        for (int q = 0; q < 4; ++q) {
            const char* vq = vt + q * (434 * 16) + base;
            float acc[8];
#pragma unroll
            for (int j = 0; j < 8; ++j) acc[j] = 0.f;
#pragma unroll
            for (int d = 0; d < 25; ++d) {
                const int dy = d / 5, dx = d % 5;
                float wf = wc[d];
                uint4v vv = *(const uint4v*)(vq + (dy * 36 + dx) * 16);
#pragma unroll
                for (int z = 0; z < 4; ++z) {
                    acc[2 * z]     += wf * bf2f_lo(vv[z]);
                    acc[2 * z + 1] += wf * bf2f_hi(vv[z]);
                }
            }
            ushort8 ov;
#pragma unroll
            for (int j = 0; j < 8; ++j) ov[j] = f2bf(acc[j]);
            *(ushort8*)(fo + q * 8) = ov;
        }
    }
}

extern "C" void kernel_launch(void* const* d_in, const int* in_sizes, int n_in,
                              void* d_out, int out_size, void* d_ws, size_t ws_size,
                              hipStream_t stream)
{
    const float* x  = (const float*)d_in[0];
    const float* Wv = (const float*)d_in[1];
    const float* Wa = (const float*)d_in[2];
    const float* ba = (const float*)d_in[3];
    const float* Wp = (const float*)d_in[4];
    const float* bp = (const float*)d_in[5];
    float* out = (float*)d_out;

    unsigned short* xt   = (unsigned short*)d_ws;        // 9,633,792 (reused as fold)
    unsigned short* V    = xt + 9633792;                 // 9,633,792
    unsigned short* AT   = V + 9633792;                  // 27,095,040
    unsigned short* Wall = AT + 27095040;                // 147,456
    unsigned short* Wpt  = Wall + 147456;                // 36,864
    float*          ball = (float*)(Wpt + 36864);        // 768 floats
    unsigned short* foldb = xt;                          // xt dead after gemm_big

    dim3 blk(256);
    prep_weights<<<576, blk, 0, stream>>>(Wv, Wa, Wp, ba, Wall, Wpt, ball);
    transpose_x<<<dim3(784, 3), blk, 0, stream>>>(x, xt);
    gemm_big<<<2352, blk, 0, stream>>>(xt, Wall, ball, V, AT);
    fused_att_agg<<<1344, blk, 0, stream>>>(V, AT, foldb);  // 16 img x 7 x 2 x 6 heads
    gemm_small<<<dim3(196, 3), blk, 0, stream>>>(Wpt, foldb, bp, out);
}

// Round 6
// 183.406 us; speedup vs baseline: 1.2168x; 1.2168x over previous
//
#include <hip/hip_runtime.h>
#include <hip/hip_bf16.h>
#include <math.h>

#define HW 3136
#define NPOS 50176          // 16 images x 3136
#define NC 192
#define NHEADS 6
#define IMG 56
#define NATT 486
#define ATT_SCALE 0.17677669529663687f  // 32^-0.5

typedef __attribute__((ext_vector_type(8))) short short8;
typedef __attribute__((ext_vector_type(8))) unsigned short ushort8;
typedef __attribute__((ext_vector_type(4))) float float4v;
typedef __attribute__((ext_vector_type(4))) unsigned int uint4v;

__device__ __forceinline__ float bf2f(unsigned short u) {
    unsigned int x = ((unsigned int)u) << 16;
    return __builtin_bit_cast(float, x);
}
__device__ __forceinline__ float bf2f_lo(unsigned int u) {
    return __builtin_bit_cast(float, u << 16);
}
__device__ __forceinline__ float bf2f_hi(unsigned int u) {
    return __builtin_bit_cast(float, u & 0xffff0000u);
}
__device__ __forceinline__ unsigned short f2bf(float f) {
    __hip_bfloat16 h = __float2bfloat16(f);
    return __builtin_bit_cast(unsigned short, h);
}
__device__ __forceinline__ void gload_lds16(const void* g, void* l) {
    __builtin_amdgcn_global_load_lds((const __attribute__((address_space(1))) void*)g,
                                     (__attribute__((address_space(3))) void*)l, 16, 0, 0);
}

// x [16][192][3136] fp32 -> xt [50176][192] bf16 (channels-last). grid (784,3), block 256.
__global__ __launch_bounds__(256) void transpose_x(const float* __restrict__ x,
                                                   unsigned short* __restrict__ xt)
{
    __shared__ float tile[64][65];
    int bx = blockIdx.x;
    int n = (bx * 64) / HW;
    int hw0 = (bx * 64) % HW;
    int c0 = blockIdx.y * 64;
    int tl = threadIdx.x & 63, tg = threadIdx.x >> 6;
    const float* xn = x + (size_t)n * NC * HW;
#pragma unroll
    for (int i = 0; i < 16; ++i)
        tile[tg * 16 + i][tl] = xn[(size_t)(c0 + tg * 16 + i) * HW + hw0 + tl];
    __syncthreads();
    unsigned short* xp = xt + ((size_t)n * HW + hw0) * NC + c0;
#pragma unroll
    for (int i = 0; i < 16; ++i) {
        int hwr = tg * 16 + i;
        xp[(size_t)hwr * NC + tl] = f2bf(tile[tl][hwr]);
    }
}

// Weight prep: Wall[768][192] = [Wv^T ; Wa^T permuted, stride 10], ball[768],
// Wpt[192][192] = Wp^T. grid 576, block 256.
__global__ __launch_bounds__(256) void prep_weights(
    const float* __restrict__ Wv, const float* __restrict__ Wa, const float* __restrict__ Wp,
    const float* __restrict__ ba,
    unsigned short* __restrict__ Wall, unsigned short* __restrict__ Wpt,
    float* __restrict__ ball)
{
    int idx = blockIdx.x * 256 + threadIdx.x;
    if (idx < 36864) {
        int d = idx / 192, k = idx - d * 192;
        Wpt[idx] = f2bf(Wp[(size_t)k * NC + d]);
    }
    if (idx < 147456) {                       // 768*192
        int d = idx / 192, k = idx - d * 192;
        unsigned short val;
        float bv = 0.f;
        if (d < 192) {
            val = f2bf(Wv[(size_t)k * NC + d]);
        } else {
            int dp = d - 192;                 // 0..575
            int head = dp / 96, rr = dp - head * 96;
            int k9 = rr / 10, l = rr - k9 * 10;
            bool valid = (k9 < 9) && (l < 9);
            int src = head * 81 + k9 * 9 + l;
            val = valid ? f2bf(Wa[(size_t)k * NATT + src]) : (unsigned short)0;
            bv = valid ? ba[src] : 0.f;
        }
        Wall[idx] = val;
        if (k == 0) ball[d] = bv;
    }
}

// GEMM over all 768 output cols; epilogue scatters into fused-friendly layouts:
//   cols [0,192)   -> V[head][pos][32]           (64-B records)
//   cols [192,768) -> AT[head*9+k9][pos][10]     (20-B records; k9==9 pads dropped)
// v10: v8 structure (LDS dbuf + counted-vmcnt 2-phase) re-partitioned across
// 8 waves (512 threads) for TLP: wave grid 2Mx4N, acc[4][2] = 32 AGPR/wave,
// ~85 regs -> 4 waves/SIMD cap; 32 KB LDS -> 2 blocks/CU x 8 waves = 16
// waves/CU (~50% occupancy vs 22% at 4 waves). Staging = exactly 1 A-load +
// 1 B-load per thread per K-step (vmcnt(2) keeps next stage in flight).
// XCD row-grouping kept: all 6 col-blocks of row-tile r on XCD r%8.
// grid 2352 (1-D), block 512.
__global__ __launch_bounds__(512, 4) void gemm_big(
    const unsigned short* __restrict__ A, const unsigned short* __restrict__ W,
    const float* __restrict__ ball,
    unsigned short* __restrict__ Vo, unsigned short* __restrict__ ATo)
{
    __shared__ __align__(16) unsigned short As[2][4096];
    __shared__ __align__(16) unsigned short Bs[2][4096];
    int t = threadIdx.x, lane = t & 63, wave = t >> 6;   // 8 waves
    int bi = blockIdx.x;
    int slot = bi >> 3;                // 0..293
    int q6 = slot / 6;
    int rr_ = (bi & 7) + 8 * q6;       // row-tile 0..391, xcd-grouped
    int cc_ = slot - 6 * q6;           // col-tile 0..5
    int col0 = cc_ * 128, row0 = rr_ * 128;
    int fr = lane & 15, fq = lane >> 4;
    int wm = (wave >> 2) * 64, wn = (wave & 3) * 32;
    const char* Ab = (const char*)A;
    const char* Wb = (const char*)W;

    float4v acc[4][2] = {};

    // thread t stages 16 B of A and 16 B of B: row = t>>2, chunk = t&3.
    // LDS dest (wave-uniform) + lane*16 == t*16 == (t>>2)*64 + (t&3)*16.
#define STAGE_BIG(buf, k0)                                                         \
    {                                                                              \
        gload_lds16(Ab + (size_t)(row0 + wave * 16 + (lane >> 2)) * 384 +          \
                        (k0) * 2 + (lane & 3) * 16,                                \
                    (char*)As[buf] + wave * 1024);                                 \
        gload_lds16(Wb + (size_t)(col0 + wave * 16 + (lane >> 2)) * 384 +          \
                        (k0) * 2 + (lane & 3) * 16,                                \
                    (char*)Bs[buf] + wave * 1024);                                 \
    }

    STAGE_BIG(0, 0);
    for (int s = 0; s < 6; ++s) {
        if (s < 5) {
            STAGE_BIG((s + 1) & 1, (s + 1) * 32);
            // wait only for current buffer's 2 loads; keep next 2 in flight
            asm volatile("s_waitcnt vmcnt(2)\n\ts_barrier" ::: "memory");
        } else {
            asm volatile("s_waitcnt vmcnt(0)\n\ts_barrier" ::: "memory");
        }
        int buf = s & 1;
        short8 af[4], bf[2];
#pragma unroll
        for (int mi = 0; mi < 4; ++mi)
            af[mi] = *(const short8*)((const char*)As[buf] + (wm + mi * 16 + fr) * 64 + fq * 16);
#pragma unroll
        for (int ni = 0; ni < 2; ++ni)
            bf[ni] = *(const short8*)((const char*)Bs[buf] + (wn + ni * 16 + fr) * 64 + fq * 16);
        // all LDS reads complete before any wave's next STAGE overwrites this buf
        asm volatile("s_waitcnt lgkmcnt(0)\n\ts_barrier" ::: "memory");
#pragma unroll
        for (int mi = 0; mi < 4; ++mi)
#pragma unroll
            for (int ni = 0; ni < 2; ++ni)
                acc[mi][ni] = __builtin_amdgcn_mfma_f32_16x16x32_bf16(
                    af[mi], bf[ni], acc[mi][ni], 0, 0, 0);
    }

#pragma unroll
    for (int ni = 0; ni < 2; ++ni) {
        int col = col0 + wn + ni * 16 + fr;
        float b = ball[col];
        unsigned short* bptr;
        size_t rstr;
        bool valid;
        if (col < 192) {
            int hd = col >> 5, ch = col & 31;
            bptr = Vo + ((size_t)hd * NPOS) * 32 + ch;
            rstr = 32;
            valid = true;
        } else {
            int dp = col - 192;
            int hd = dp / 96, rr = dp - hd * 96;
            int k9 = rr / 10, l = rr - k9 * 10;
            valid = (k9 < 9);
            bptr = ATo + ((size_t)(hd * 9 + (k9 < 9 ? k9 : 8)) * NPOS) * 10 + l;
            rstr = 10;
        }
#pragma unroll
        for (int mi = 0; mi < 4; ++mi) {
            int row = row0 + wm + mi * 16 + fq * 4;
#pragma unroll
            for (int r = 0; r < 4; ++r) {
                unsigned short val = f2bf(acc[mi][ni][r] + b);
                if (valid) bptr[(size_t)(row + r) * rstr] = val;
            }
        }
    }
#undef STAGE_BIG
}

// out[img][m][phw] = sum_k Wpt[m][k]*fold[n][k] + bias[m]; 64(m) x 256(n) tile.
// grid (196, 3), block 256, 4 waves each 64x64. v8: counted-vmcnt 2-phase.
__global__ __launch_bounds__(256) void gemm_small(
    const unsigned short* __restrict__ A,   // Wpt [192][192]
    const unsigned short* __restrict__ B,   // fold [50176][192]
    const float* __restrict__ bias, float* __restrict__ out)
{
    __shared__ __align__(16) unsigned short As[2][2048];
    __shared__ __align__(16) unsigned short Bs[2][8192];
    int t = threadIdx.x, lane = t & 63, wave = t >> 6;
    int n0 = blockIdx.x * 256, m0 = blockIdx.y * 64;
    int fr = lane & 15, fq = lane >> 4;
    int srow = lane >> 2, soff = (lane & 3) * 16;
    const char* Ab = (const char*)A;
    const char* Bb = (const char*)B;

    float4v acc[4][4] = {};

#define STAGE_SMALL(buf, k0)                                                      \
    {                                                                             \
        gload_lds16(Ab + (size_t)(m0 + wave * 16 + srow) * 384 + (k0)*2 + soff,   \
                    (char*)As[buf] + wave * 1024);                                \
        _Pragma("unroll")                                                         \
        for (int i = 0; i < 4; ++i) {                                             \
            int j = wave * 4 + i;                                                 \
            gload_lds16(Bb + (size_t)(n0 + j * 16 + srow) * 384 + (k0)*2 + soff,  \
                        (char*)Bs[buf] + j * 1024);                               \
        }                                                                         \
    }

    STAGE_SMALL(0, 0);
    for (int s = 0; s < 6; ++s) {
        if (s < 5) {
            STAGE_SMALL((s + 1) & 1, (s + 1) * 32);
            // wait only for current buffer's 5 loads; keep next 5 in flight
            asm volatile("s_waitcnt vmcnt(5)\n\ts_barrier" ::: "memory");
        } else {
            asm volatile("s_waitcnt vmcnt(0)\n\ts_barrier" ::: "memory");
        }
        int buf = s & 1;
        short8 af[4], bf[4];
#pragma unroll
        for (int mi = 0; mi < 4; ++mi)
            af[mi] = *(const short8*)((const char*)As[buf] + (mi * 16 + fr) * 64 + fq * 16);
#pragma unroll
        for (int ni = 0; ni < 4; ++ni)
            bf[ni] = *(const short8*)((const char*)Bs[buf] + (wave * 64 + ni * 16 + fr) * 64 + fq * 16);
        asm volatile("s_waitcnt lgkmcnt(0)\n\ts_barrier" ::: "memory");
#pragma unroll
        for (int mi = 0; mi < 4; ++mi)
#pragma unroll
            for (int ni = 0; ni < 4; ++ni)
                acc[mi][ni] = __builtin_amdgcn_mfma_f32_16x16x32_bf16(
                    af[mi], bf[ni], acc[mi][ni], 0, 0, 0);
    }

#pragma unroll
    for (int ni = 0; ni < 4; ++ni) {
        int n = n0 + wave * 64 + ni * 16 + fr;
        int img = n / HW, phw = n - img * HW;
        float* op = out + (size_t)img * (NC * HW) + phw;
#pragma unroll
        for (int mi = 0; mi < 4; ++mi) {
            int m = m0 + mi * 16 + fq * 4;
#pragma unroll
            for (int r = 0; r < 4; ++r)
                op[(size_t)(m + r) * HW] = acc[mi][ni][r] + bias[m + r];
        }
    }
#undef STAGE_SMALL
}

// Fused softmax + weight-combine + aggregation, v7: coalesced global layouts.
// Block = one head x (8x28) image tile (224 positions, 256 threads).
//  - V[head][pos][32]: halo staging reads are fully contiguous per wave.
//  - AT[head*9+k][pos][10]: softmax tap k reads consecutive pos across lanes.
//  - LDS: 4 q-planes, plane stride 434 chunks (16 B each; 434 mod 8 = 2 makes
//    the interleaved write mapping q=u&3 hit every bank-quad exactly 2x per
//    16-lane phase), row stride 36 chunks (read-balanced for the 28-wide map).
__global__ __launch_bounds__(256, 4) void fused_att_agg(
    const unsigned short* __restrict__ V, const unsigned short* __restrict__ AT,
    unsigned short* __restrict__ fold)
{
    __shared__ __align__(16) char vt[4 * 434 * 16];   // 27776 B
    int t = threadIdx.x;
    int bid = blockIdx.x;
    int head = bid % NHEADS; int tmp = bid / NHEADS;
    int tcol = tmp & 1; tmp >>= 1;
    int trow = tmp % 7; int img = tmp / 7;
    int h0 = trow * 8, w0 = tcol * 28;

    // ---- issue v-halo loads into registers (clamped addr + zero mask) ----
    const unsigned short* Vh = V + (size_t)head * NPOS * 32;
    ushort8 stg[6];
#pragma unroll
    for (int i = 0; i < 6; ++i) {
        int u = i * 256 + t;                 // 0..1535
        int slot = u >> 2, q = u & 3;        // slot = vrow*32+vcol, q = 16-B quarter
        int vrow = slot >> 5, vcol = slot & 31;
        int hh = h0 - 2 + vrow, ww = w0 - 2 + vcol;
        bool ok = (hh >= 0) & (hh < IMG) & (ww >= 0) & (ww < IMG);
        int hc = min(max(hh, 0), IMG - 1);
        int wcl = min(max(ww, 0), IMG - 1);
        ushort8 val = *(const ushort8*)(Vh + (size_t)(img * HW + hc * IMG + wcl) * 32 + q * 8);
        if (!ok) val = (ushort8){};
        stg[i] = val;
    }

    // ---- softmax -> 5x5 stencil weights, fully in registers ----
    int ph = t / 28, pw = t - (t / 28) * 28;
    int h = h0 + ph, w = w0 + pw;
    float wc[25];
#pragma unroll
    for (int d = 0; d < 25; ++d) wc[d] = 0.f;
    if (t < 224) {
        int head9 = head * 9;
#pragma unroll
        for (int k = 0; k < 9; ++k) {
            const int oky = k / 3 - 1, okx = k % 3 - 1;
            int hh = h - oky, ww = w - okx;
            bool ok = (hh >= 0) & (hh < IMG) & (ww >= 0) & (ww < IMG);
            int hc = min(max(hh, 0), IMG - 1);
            int wcl = min(max(ww, 0), IMG - 1);
            size_t nidx = (size_t)img * HW + hc * IMG + wcl;
            const unsigned int* ap32 =
                (const unsigned int*)(AT + ((size_t)(head9 + k) * NPOS + nidx) * 10);
            unsigned int u0 = ap32[0], u1 = ap32[1], u2 = ap32[2], u3 = ap32[3], u4 = ap32[4];
            float a[9] = { bf2f_lo(u0), bf2f_hi(u0), bf2f_lo(u1), bf2f_hi(u1),
                           bf2f_lo(u2), bf2f_hi(u2), bf2f_lo(u3), bf2f_hi(u3),
                           bf2f_lo(u4) };
            float m = -1e30f;
#pragma unroll
            for (int l = 0; l < 9; ++l) m = fmaxf(m, a[l]);
            float s = 0.f;
#pragma unroll
            for (int l = 0; l < 9; ++l) {
                a[l] = __expf((a[l] - m) * ATT_SCALE);
                s += a[l];
            }
            float g = ok ? (1.f / s) : 0.f;   // invalid neighbor contributes 0
#pragma unroll
            for (int l = 0; l < 9; ++l) {
                const int dy = (l / 3 - 1) - oky + 2;
                const int dx = (l % 3 - 1) - okx + 2;
                wc[dy * 5 + dx] += a[l] * g;
            }
        }
    }

    // ---- commit staged halo to LDS (write-balanced: plane stride 2 mod 8) ----
#pragma unroll
    for (int i = 0; i < 6; ++i) {
        int u = i * 256 + t;
        int slot = u >> 2, q = u & 3;
        int vrow = slot >> 5, vcol = slot & 31;
        *(ushort8*)(vt + q * (434 * 16) + (vrow * 36 + vcol) * 16) = stg[i];
    }
    __syncthreads();

    // ---- aggregate: 25 taps x 4 quarters, read-balanced, imm offsets ----
    if (t < 224) {
        int base = (ph * 36 + pw) * 16;
        int pos = img * HW + h * IMG + w;
        unsigned short* fo = fold + (size_t)pos * NC + head * 32;
#pragma unroll
        for (int q = 0; q < 4; ++q) {
            const char* vq = vt + q * (434 * 16) + base;
            float acc[8];
#pragma unroll
            for (int j = 0; j < 8; ++j) acc[j] = 0.f;
#pragma unroll
            for (int d = 0; d < 25; ++d) {
                const int dy = d / 5, dx = d % 5;
                float wf = wc[d];
                uint4v vv = *(const uint4v*)(vq + (dy * 36 + dx) * 16);
#pragma unroll
                for (int z = 0; z < 4; ++z) {
                    acc[2 * z]     += wf * bf2f_lo(vv[z]);
                    acc[2 * z + 1] += wf * bf2f_hi(vv[z]);
                }
            }
            ushort8 ov;
#pragma unroll
            for (int j = 0; j < 8; ++j) ov[j] = f2bf(acc[j]);
            *(ushort8*)(fo + q * 8) = ov;
        }
    }
}

extern "C" void kernel_launch(void* const* d_in, const int* in_sizes, int n_in,
                              void* d_out, int out_size, void* d_ws, size_t ws_size,
                              hipStream_t stream)
{
    const float* x  = (const float*)d_in[0];
    const float* Wv = (const float*)d_in[1];
    const float* Wa = (const float*)d_in[2];
    const float* ba = (const float*)d_in[3];
    const float* Wp = (const float*)d_in[4];
    const float* bp = (const float*)d_in[5];
    float* out = (float*)d_out;

    unsigned short* xt   = (unsigned short*)d_ws;        // 9,633,792 (reused as fold)
    unsigned short* V    = xt + 9633792;                 // 9,633,792
    unsigned short* AT   = V + 9633792;                  // 27,095,040
    unsigned short* Wall = AT + 27095040;                // 147,456
    unsigned short* Wpt  = Wall + 147456;                // 36,864
    float*          ball = (float*)(Wpt + 36864);        // 768 floats
    unsigned short* foldb = xt;                          // xt dead after gemm_big

    dim3 blk(256);
    prep_weights<<<576, blk, 0, stream>>>(Wv, Wa, Wp, ba, Wall, Wpt, ball);
    transpose_x<<<dim3(784, 3), blk, 0, stream>>>(x, xt);
    gemm_big<<<2352, dim3(512), 0, stream>>>(xt, Wall, ball, V, AT);
    fused_att_agg<<<1344, blk, 0, stream>>>(V, AT, foldb);  // 16 img x 7 x 2 x 6 heads
    gemm_small<<<dim3(196, 3), blk, 0, stream>>>(Wpt, foldb, bp, out);
}

// Round 7
// 182.933 us; speedup vs baseline: 1.2200x; 1.0026x over previous
//
#include <hip/hip_runtime.h>
#include <hip/hip_bf16.h>
#include <math.h>

#define HW 3136
#define NPOS 50176          // 16 images x 3136
#define NC 192
#define NHEADS 6
#define IMG 56
#define NATT 486
#define ATT_SCALE 0.17677669529663687f  // 32^-0.5

typedef __attribute__((ext_vector_type(8))) short short8;
typedef __attribute__((ext_vector_type(8))) unsigned short ushort8;
typedef __attribute__((ext_vector_type(4))) float float4v;
typedef __attribute__((ext_vector_type(4))) unsigned int uint4v;

__device__ __forceinline__ float bf2f(unsigned short u) {
    unsigned int x = ((unsigned int)u) << 16;
    return __builtin_bit_cast(float, x);
}
__device__ __forceinline__ float bf2f_lo(unsigned int u) {
    return __builtin_bit_cast(float, u << 16);
}
__device__ __forceinline__ float bf2f_hi(unsigned int u) {
    return __builtin_bit_cast(float, u & 0xffff0000u);
}
__device__ __forceinline__ unsigned short f2bf(float f) {
    __hip_bfloat16 h = __float2bfloat16(f);
    return __builtin_bit_cast(unsigned short, h);
}
__device__ __forceinline__ void gload_lds16(const void* g, void* l) {
    __builtin_amdgcn_global_load_lds((const __attribute__((address_space(1))) void*)g,
                                     (__attribute__((address_space(3))) void*)l, 16, 0, 0);
}

// x [16][192][3136] fp32 -> xt [50176][192] bf16 (channels-last). grid (784,3), block 256.
__global__ __launch_bounds__(256) void transpose_x(const float* __restrict__ x,
                                                   unsigned short* __restrict__ xt)
{
    __shared__ float tile[64][65];
    int bx = blockIdx.x;
    int n = (bx * 64) / HW;
    int hw0 = (bx * 64) % HW;
    int c0 = blockIdx.y * 64;
    int tl = threadIdx.x & 63, tg = threadIdx.x >> 6;
    const float* xn = x + (size_t)n * NC * HW;
#pragma unroll
    for (int i = 0; i < 16; ++i)
        tile[tg * 16 + i][tl] = xn[(size_t)(c0 + tg * 16 + i) * HW + hw0 + tl];
    __syncthreads();
    unsigned short* xp = xt + ((size_t)n * HW + hw0) * NC + c0;
#pragma unroll
    for (int i = 0; i < 16; ++i) {
        int hwr = tg * 16 + i;
        xp[(size_t)hwr * NC + tl] = f2bf(tile[tl][hwr]);
    }
}

// Weight prep: Wall[768][192] = [Wv^T ; Wa^T permuted, stride 10], ball[768],
// Wpt[192][192] = Wp^T. grid 576, block 256.
__global__ __launch_bounds__(256) void prep_weights(
    const float* __restrict__ Wv, const float* __restrict__ Wa, const float* __restrict__ Wp,
    const float* __restrict__ ba,
    unsigned short* __restrict__ Wall, unsigned short* __restrict__ Wpt,
    float* __restrict__ ball)
{
    int idx = blockIdx.x * 256 + threadIdx.x;
    if (idx < 36864) {
        int d = idx / 192, k = idx - d * 192;
        Wpt[idx] = f2bf(Wp[(size_t)k * NC + d]);
    }
    if (idx < 147456) {                       // 768*192
        int d = idx / 192, k = idx - d * 192;
        unsigned short val;
        float bv = 0.f;
        if (d < 192) {
            val = f2bf(Wv[(size_t)k * NC + d]);
        } else {
            int dp = d - 192;                 // 0..575
            int head = dp / 96, rr = dp - head * 96;
            int k9 = rr / 10, l = rr - k9 * 10;
            bool valid = (k9 < 9) && (l < 9);
            int src = head * 81 + k9 * 9 + l;
            val = valid ? f2bf(Wa[(size_t)k * NATT + src]) : (unsigned short)0;
            bv = valid ? ba[src] : 0.f;
        }
        Wall[idx] = val;
        if (k == 0) ball[d] = bv;
    }
}

// GEMM over all 768 output cols; epilogue scatters into fused-friendly layouts:
//   cols [0,192)   -> V[head][pos][32]           (64-B records)
//   cols [192,768) -> AT[head*9+k9][pos][10]     (20-B records; k9==9 pads dropped)
// v11: 8 waves (2Mx4N, acc[4][2]) + 3-buffer distance-2 prefetch (vmcnt(4):
// the wait per step drops from lat-1*step to lat-2*step) + XOR bank swizzle:
// LDS dest stays linear (global_load_lds requirement); global SOURCE chunk is
// pre-permuted g=(lane&3)^((lane>>3)&3) and the fragment read uses chunk
// fq^((fr>>1)&3) -> quarter-wave bank-quads {0,4,1,5,2,6,3,7} = 2-way (free).
// XCD row-grouping kept: all 6 col-blocks of row-tile r on XCD r%8.
// grid 2352 (1-D), block 512. LDS 48 KB -> 3 blocks/CU, 24 waves/CU.
__global__ __launch_bounds__(512, 4) void gemm_big(
    const unsigned short* __restrict__ A, const unsigned short* __restrict__ W,
    const float* __restrict__ ball,
    unsigned short* __restrict__ Vo, unsigned short* __restrict__ ATo)
{
    __shared__ __align__(16) unsigned short As[3][4096];
    __shared__ __align__(16) unsigned short Bs[3][4096];
    int t = threadIdx.x, lane = t & 63, wave = t >> 6;   // 8 waves
    int bi = blockIdx.x;
    int slot = bi >> 3;                // 0..293
    int q6 = slot / 6;
    int rr_ = (bi & 7) + 8 * q6;       // row-tile 0..391, xcd-grouped
    int cc_ = slot - 6 * q6;           // col-tile 0..5
    int col0 = cc_ * 128, row0 = rr_ * 128;
    int fr = lane & 15, fq = lane >> 4;
    int wm = (wave >> 2) * 64, wn = (wave & 3) * 32;
    int srow = lane >> 2;                                // staged row within wave's 16
    int sg = ((lane & 3) ^ ((lane >> 3) & 3)) * 16;      // pre-swizzled source chunk
    int rc = (fq ^ ((fr >> 1) & 3)) * 16;                // swizzled read chunk
    const char* Ab = (const char*)A;
    const char* Wb = (const char*)W;

    float4v acc[4][2] = {};

    // LDS stays linear: offset = wave*1024 + lane*16 = row*64 + (lane&3)*16.
    // Slot (row, c) holds global chunk c ^ ((row>>1)&3) = c ^ ((lane>>3)&3).
#define STAGE_BIG(buf, k0)                                                         \
    {                                                                              \
        gload_lds16(Ab + (size_t)(row0 + wave * 16 + srow) * 384 + (k0) * 2 + sg,  \
                    (char*)As[buf] + wave * 1024);                                 \
        gload_lds16(Wb + (size_t)(col0 + wave * 16 + srow) * 384 + (k0) * 2 + sg,  \
                    (char*)Bs[buf] + wave * 1024);                                 \
    }

    STAGE_BIG(0, 0);
    STAGE_BIG(1, 32);
#pragma unroll
    for (int s = 0; s < 6; ++s) {
        int buf = s % 3;
        if (s < 4) {
            STAGE_BIG((s + 2) % 3, (s + 2) * 32);
            // buf s ready when only stages s+1,s+2 (4 loads) remain in flight
            asm volatile("s_waitcnt vmcnt(4)\n\ts_barrier" ::: "memory");
        } else if (s == 4) {
            asm volatile("s_waitcnt vmcnt(2)\n\ts_barrier" ::: "memory");
        } else {
            asm volatile("s_waitcnt vmcnt(0)\n\ts_barrier" ::: "memory");
        }
        short8 af[4], bf[2];
#pragma unroll
        for (int mi = 0; mi < 4; ++mi)
            af[mi] = *(const short8*)((const char*)As[buf] + (wm + mi * 16 + fr) * 64 + rc);
#pragma unroll
        for (int ni = 0; ni < 2; ++ni)
            bf[ni] = *(const short8*)((const char*)Bs[buf] + (wn + ni * 16 + fr) * 64 + rc);
        // reads of buf (s-1)%3 == (s+2)%3 done before next iter's stage lands
        asm volatile("s_waitcnt lgkmcnt(0)\n\ts_barrier" ::: "memory");
#pragma unroll
        for (int mi = 0; mi < 4; ++mi)
#pragma unroll
            for (int ni = 0; ni < 2; ++ni)
                acc[mi][ni] = __builtin_amdgcn_mfma_f32_16x16x32_bf16(
                    af[mi], bf[ni], acc[mi][ni], 0, 0, 0);
    }

#pragma unroll
    for (int ni = 0; ni < 2; ++ni) {
        int col = col0 + wn + ni * 16 + fr;
        float b = ball[col];
        unsigned short* bptr;
        size_t rstr;
        bool valid;
        if (col < 192) {
            int hd = col >> 5, ch = col & 31;
            bptr = Vo + ((size_t)hd * NPOS) * 32 + ch;
            rstr = 32;
            valid = true;
        } else {
            int dp = col - 192;
            int hd = dp / 96, rr = dp - hd * 96;
            int k9 = rr / 10, l = rr - k9 * 10;
            valid = (k9 < 9);
            bptr = ATo + ((size_t)(hd * 9 + (k9 < 9 ? k9 : 8)) * NPOS) * 10 + l;
            rstr = 10;
        }
#pragma unroll
        for (int mi = 0; mi < 4; ++mi) {
            int row = row0 + wm + mi * 16 + fq * 4;
#pragma unroll
            for (int r = 0; r < 4; ++r) {
                unsigned short val = f2bf(acc[mi][ni][r] + b);
                if (valid) bptr[(size_t)(row + r) * rstr] = val;
            }
        }
    }
#undef STAGE_BIG
}

// out[img][m][phw] = sum_k Wpt[m][k]*fold[n][k] + bias[m]; 64(m) x 256(n) tile.
// grid (196, 3), block 256, 4 waves each 64x64. v11: counted-vmcnt 2-phase
// + XOR bank swizzle (same scheme as gemm_big; 2 buffers kept - 3 would halve
// occupancy via LDS).
__global__ __launch_bounds__(256) void gemm_small(
    const unsigned short* __restrict__ A,   // Wpt [192][192]
    const unsigned short* __restrict__ B,   // fold [50176][192]
    const float* __restrict__ bias, float* __restrict__ out)
{
    __shared__ __align__(16) unsigned short As[2][2048];
    __shared__ __align__(16) unsigned short Bs[2][8192];
    int t = threadIdx.x, lane = t & 63, wave = t >> 6;
    int n0 = blockIdx.x * 256, m0 = blockIdx.y * 64;
    int fr = lane & 15, fq = lane >> 4;
    int srow = lane >> 2;
    int sg = ((lane & 3) ^ ((lane >> 3) & 3)) * 16;      // pre-swizzled source chunk
    int rc = (fq ^ ((fr >> 1) & 3)) * 16;                // swizzled read chunk
    const char* Ab = (const char*)A;
    const char* Bb = (const char*)B;

    float4v acc[4][4] = {};

#define STAGE_SMALL(buf, k0)                                                      \
    {                                                                             \
        gload_lds16(Ab + (size_t)(m0 + wave * 16 + srow) * 384 + (k0)*2 + sg,     \
                    (char*)As[buf] + wave * 1024);                                \
        _Pragma("unroll")                                                         \
        for (int i = 0; i < 4; ++i) {                                             \
            int j = wave * 4 + i;                                                 \
            gload_lds16(Bb + (size_t)(n0 + j * 16 + srow) * 384 + (k0)*2 + sg,    \
                        (char*)Bs[buf] + j * 1024);                               \
        }                                                                         \
    }

    STAGE_SMALL(0, 0);
    for (int s = 0; s < 6; ++s) {
        if (s < 5) {
            STAGE_SMALL((s + 1) & 1, (s + 1) * 32);
            // wait only for current buffer's 5 loads; keep next 5 in flight
            asm volatile("s_waitcnt vmcnt(5)\n\ts_barrier" ::: "memory");
        } else {
            asm volatile("s_waitcnt vmcnt(0)\n\ts_barrier" ::: "memory");
        }
        int buf = s & 1;
        short8 af[4], bf[4];
#pragma unroll
        for (int mi = 0; mi < 4; ++mi)
            af[mi] = *(const short8*)((const char*)As[buf] + (mi * 16 + fr) * 64 + rc);
#pragma unroll
        for (int ni = 0; ni < 4; ++ni)
            bf[ni] = *(const short8*)((const char*)Bs[buf] + (wave * 64 + ni * 16 + fr) * 64 + rc);
        asm volatile("s_waitcnt lgkmcnt(0)\n\ts_barrier" ::: "memory");
#pragma unroll
        for (int mi = 0; mi < 4; ++mi)
#pragma unroll
            for (int ni = 0; ni < 4; ++ni)
                acc[mi][ni] = __builtin_amdgcn_mfma_f32_16x16x32_bf16(
                    af[mi], bf[ni], acc[mi][ni], 0, 0, 0);
    }

#pragma unroll
    for (int ni = 0; ni < 4; ++ni) {
        int n = n0 + wave * 64 + ni * 16 + fr;
        int img = n / HW, phw = n - img * HW;
        float* op = out + (size_t)img * (NC * HW) + phw;
#pragma unroll
        for (int mi = 0; mi < 4; ++mi) {
            int m = m0 + mi * 16 + fq * 4;
#pragma unroll
            for (int r = 0; r < 4; ++r)
                op[(size_t)(m + r) * HW] = acc[mi][ni][r] + bias[m + r];
        }
    }
#undef STAGE_SMALL
}

// Fused softmax + weight-combine + aggregation, v7: coalesced global layouts.
// Block = one head x (8x28) image tile (224 positions, 256 threads).
//  - V[head][pos][32]: halo staging reads are fully contiguous per wave.
//  - AT[head*9+k][pos][10]: softmax tap k reads consecutive pos across lanes.
//  - LDS: 4 q-planes, plane stride 434 chunks (16 B each; 434 mod 8 = 2 makes
//    the interleaved write mapping q=u&3 hit every bank-quad exactly 2x per
//    16-lane phase), row stride 36 chunks (read-balanced for the 28-wide map).
__global__ __launch_bounds__(256, 4) void fused_att_agg(
    const unsigned short* __restrict__ V, const unsigned short* __restrict__ AT,
    unsigned short* __restrict__ fold)
{
    __shared__ __align__(16) char vt[4 * 434 * 16];   // 27776 B
    int t = threadIdx.x;
    int bid = blockIdx.x;
    int head = bid % NHEADS; int tmp = bid / NHEADS;
    int tcol = tmp & 1; tmp >>= 1;
    int trow = tmp % 7; int img = tmp / 7;
    int h0 = trow * 8, w0 = tcol * 28;

    // ---- issue v-halo loads into registers (clamped addr + zero mask) ----
    const unsigned short* Vh = V + (size_t)head * NPOS * 32;
    ushort8 stg[6];
#pragma unroll
    for (int i = 0; i < 6; ++i) {
        int u = i * 256 + t;                 // 0..1535
        int slot = u >> 2, q = u & 3;        // slot = vrow*32+vcol, q = 16-B quarter
        int vrow = slot >> 5, vcol = slot & 31;
        int hh = h0 - 2 + vrow, ww = w0 - 2 + vcol;
        bool ok = (hh >= 0) & (hh < IMG) & (ww >= 0) & (ww < IMG);
        int hc = min(max(hh, 0), IMG - 1);
        int wcl = min(max(ww, 0), IMG - 1);
        ushort8 val = *(const ushort8*)(Vh + (size_t)(img * HW + hc * IMG + wcl) * 32 + q * 8);
        if (!ok) val = (ushort8){};
        stg[i] = val;
    }

    // ---- softmax -> 5x5 stencil weights, fully in registers ----
    int ph = t / 28, pw = t - (t / 28) * 28;
    int h = h0 + ph, w = w0 + pw;
    float wc[25];
#pragma unroll
    for (int d = 0; d < 25; ++d) wc[d] = 0.f;
    if (t < 224) {
        int head9 = head * 9;
#pragma unroll
        for (int k = 0; k < 9; ++k) {
            const int oky = k / 3 - 1, okx = k % 3 - 1;
            int hh = h - oky, ww = w - okx;
            bool ok = (hh >= 0) & (hh < IMG) & (ww >= 0) & (ww < IMG);
            int hc = min(max(hh, 0), IMG - 1);
            int wcl = min(max(ww, 0), IMG - 1);
            size_t nidx = (size_t)img * HW + hc * IMG + wcl;
            const unsigned int* ap32 =
                (const unsigned int*)(AT + ((size_t)(head9 + k) * NPOS + nidx) * 10);
            unsigned int u0 = ap32[0], u1 = ap32[1], u2 = ap32[2], u3 = ap32[3], u4 = ap32[4];
            float a[9] = { bf2f_lo(u0), bf2f_hi(u0), bf2f_lo(u1), bf2f_hi(u1),
                           bf2f_lo(u2), bf2f_hi(u2), bf2f_lo(u3), bf2f_hi(u3),
                           bf2f_lo(u4) };
            float m = -1e30f;
#pragma unroll
            for (int l = 0; l < 9; ++l) m = fmaxf(m, a[l]);
            float s = 0.f;
#pragma unroll
            for (int l = 0; l < 9; ++l) {
                a[l] = __expf((a[l] - m) * ATT_SCALE);
                s += a[l];
            }
            float g = ok ? (1.f / s) : 0.f;   // invalid neighbor contributes 0
#pragma unroll
            for (int l = 0; l < 9; ++l) {
                const int dy = (l / 3 - 1) - oky + 2;
                const int dx = (l % 3 - 1) - okx + 2;
                wc[dy * 5 + dx] += a[l] * g;
            }
        }
    }

    // ---- commit staged halo to LDS (write-balanced: plane stride 2 mod 8) ----
#pragma unroll
    for (int i = 0; i < 6; ++i) {
        int u = i * 256 + t;
        int slot = u >> 2, q = u & 3;
        int vrow = slot >> 5, vcol = slot & 31;
        *(ushort8*)(vt + q * (434 * 16) + (vrow * 36 + vcol) * 16) = stg[i];
    }
    __syncthreads();

    // ---- aggregate: 25 taps x 4 quarters, read-balanced, imm offsets ----
    if (t < 224) {
        int base = (ph * 36 + pw) * 16;
        int pos = img * HW + h * IMG + w;
        unsigned short* fo = fold + (size_t)pos * NC + head * 32;
#pragma unroll
        for (int q = 0; q < 4; ++q) {
            const char* vq = vt + q * (434 * 16) + base;
            float acc[8];
#pragma unroll
            for (int j = 0; j < 8; ++j) acc[j] = 0.f;
#pragma unroll
            for (int d = 0; d < 25; ++d) {
                const int dy = d / 5, dx = d % 5;
                float wf = wc[d];
                uint4v vv = *(const uint4v*)(vq + (dy * 36 + dx) * 16);
#pragma unroll
                for (int z = 0; z < 4; ++z) {
                    acc[2 * z]     += wf * bf2f_lo(vv[z]);
                    acc[2 * z + 1] += wf * bf2f_hi(vv[z]);
                }
            }
            ushort8 ov;
#pragma unroll
            for (int j = 0; j < 8; ++j) ov[j] = f2bf(acc[j]);
            *(ushort8*)(fo + q * 8) = ov;
        }
    }
}

extern "C" void kernel_launch(void* const* d_in, const int* in_sizes, int n_in,
                              void* d_out, int out_size, void* d_ws, size_t ws_size,
                              hipStream_t stream)
{
    const float* x  = (const float*)d_in[0];
    const float* Wv = (const float*)d_in[1];
    const float* Wa = (const float*)d_in[2];
    const float* ba = (const float*)d_in[3];
    const float* Wp = (const float*)d_in[4];
    const float* bp = (const float*)d_in[5];
    float* out = (float*)d_out;

    unsigned short* xt   = (unsigned short*)d_ws;        // 9,633,792 (reused as fold)
    unsigned short* V    = xt + 9633792;                 // 9,633,792
    unsigned short* AT   = V + 9633792;                  // 27,095,040
    unsigned short* Wall = AT + 27095040;                // 147,456
    unsigned short* Wpt  = Wall + 147456;                // 36,864
    float*          ball = (float*)(Wpt + 36864);        // 768 floats
    unsigned short* foldb = xt;                          // xt dead after gemm_big

    dim3 blk(256);
    prep_weights<<<576, blk, 0, stream>>>(Wv, Wa, Wp, ba, Wall, Wpt, ball);
    transpose_x<<<dim3(784, 3), blk, 0, stream>>>(x, xt);
    gemm_big<<<2352, dim3(512), 0, stream>>>(xt, Wall, ball, V, AT);
    fused_att_agg<<<1344, blk, 0, stream>>>(V, AT, foldb);  // 16 img x 7 x 2 x 6 heads
    gemm_small<<<dim3(196, 3), blk, 0, stream>>>(Wpt, foldb, bp, out);
}

// Round 8
// 170.860 us; speedup vs baseline: 1.3062x; 1.0707x over previous
//
#include <hip/hip_runtime.h>
#include <hip/hip_bf16.h>
#include <math.h>

#define HW 3136
#define NPOS 50176          // 16 images x 3136
#define NC 192
#define NHEADS 6
#define IMG 56
#define NATT 486
#define ATT_SCALE 0.17677669529663687f  // 32^-0.5

typedef __attribute__((ext_vector_type(8))) short short8;
typedef __attribute__((ext_vector_type(8))) unsigned short ushort8;
typedef __attribute__((ext_vector_type(4))) float float4v;
typedef __attribute__((ext_vector_type(4))) unsigned int uint4v;
typedef __attribute__((ext_vector_type(2))) unsigned int uint2v;

__device__ __forceinline__ float bf2f(unsigned short u) {
    unsigned int x = ((unsigned int)u) << 16;
    return __builtin_bit_cast(float, x);
}
__device__ __forceinline__ float bf2f_lo(unsigned int u) {
    return __builtin_bit_cast(float, u << 16);
}
__device__ __forceinline__ float bf2f_hi(unsigned int u) {
    return __builtin_bit_cast(float, u & 0xffff0000u);
}
__device__ __forceinline__ unsigned short f2bf(float f) {
    __hip_bfloat16 h = __float2bfloat16(f);
    return __builtin_bit_cast(unsigned short, h);
}
__device__ __forceinline__ unsigned int pack2bf(float a, float b) {
    return (unsigned int)f2bf(a) | ((unsigned int)f2bf(b) << 16);
}
__device__ __forceinline__ void gload_lds16(const void* g, void* l) {
    __builtin_amdgcn_global_load_lds((const __attribute__((address_space(1))) void*)g,
                                     (__attribute__((address_space(3))) void*)l, 16, 0, 0);
}

// x [16][192][3136] fp32 -> xt [50176][192] bf16 (channels-last). grid (784,3), block 256.
__global__ __launch_bounds__(256) void transpose_x(const float* __restrict__ x,
                                                   unsigned short* __restrict__ xt)
{
    __shared__ float tile[64][65];
    int bx = blockIdx.x;
    int n = (bx * 64) / HW;
    int hw0 = (bx * 64) % HW;
    int c0 = blockIdx.y * 64;
    int tl = threadIdx.x & 63, tg = threadIdx.x >> 6;
    const float* xn = x + (size_t)n * NC * HW;
#pragma unroll
    for (int i = 0; i < 16; ++i)
        tile[tg * 16 + i][tl] = xn[(size_t)(c0 + tg * 16 + i) * HW + hw0 + tl];
    __syncthreads();
    unsigned short* xp = xt + ((size_t)n * HW + hw0) * NC + c0;
#pragma unroll
    for (int i = 0; i < 16; ++i) {
        int hwr = tg * 16 + i;
        xp[(size_t)hwr * NC + tl] = f2bf(tile[tl][hwr]);
    }
}

// Weight prep: Wall[768][192] = [Wv^T ; Wa^T permuted, stride 10], ball[768],
// Wpt[192][192] = Wp^T. grid 576, block 256.
__global__ __launch_bounds__(256) void prep_weights(
    const float* __restrict__ Wv, const float* __restrict__ Wa, const float* __restrict__ Wp,
    const float* __restrict__ ba,
    unsigned short* __restrict__ Wall, unsigned short* __restrict__ Wpt,
    float* __restrict__ ball)
{
    int idx = blockIdx.x * 256 + threadIdx.x;
    if (idx < 36864) {
        int d = idx / 192, k = idx - d * 192;
        Wpt[idx] = f2bf(Wp[(size_t)k * NC + d]);
    }
    if (idx < 147456) {                       // 768*192
        int d = idx / 192, k = idx - d * 192;
        unsigned short val;
        float bv = 0.f;
        if (d < 192) {
            val = f2bf(Wv[(size_t)k * NC + d]);
        } else {
            int dp = d - 192;                 // 0..575
            int head = dp / 96, rr = dp - head * 96;
            int k9 = rr / 10, l = rr - k9 * 10;
            bool valid = (k9 < 9) && (l < 9);
            int src = head * 81 + k9 * 9 + l;
            val = valid ? f2bf(Wa[(size_t)k * NATT + src]) : (unsigned short)0;
            bv = valid ? ba[src] : 0.f;
        }
        Wall[idx] = val;
        if (k == 0) ball[d] = bv;
    }
}

// GEMM over all 768 output cols; epilogue scatters into fused-friendly layouts:
//   cols [0,192)   -> V[head][pos][32]           (64-B records)
//   cols [192,768) -> AT[head*9+k9][pos][10]     (20-B records; k9==9 pads dropped)
// v12: operand-swapped MFMA epilogue. mfma(bf, af) puts OUTPUT COLS on the
// reg index r (C/D layout: row = first operand, col = lane&15): each thread
// holds 4 consecutive cols per acc -> stores pack into dword/dwordx2.
// 32 scalar 2-B stores/thread -> ~16 packed stores. Col-group base
// cb = col0+wn+ni*16+fq*4 is quarter-uniform and %4==0; AT's l lands even
// (record splits at l=6/8 handled uniformly). K-loop = v11 (3-buf dist-2,
// XOR swizzle, 0 bank conflicts). XCD row-grouping kept.
// grid 2352 (1-D), block 512.
__global__ __launch_bounds__(512, 4) void gemm_big(
    const unsigned short* __restrict__ A, const unsigned short* __restrict__ W,
    const float* __restrict__ ball,
    unsigned short* __restrict__ Vo, unsigned short* __restrict__ ATo)
{
    __shared__ __align__(16) unsigned short As[3][4096];
    __shared__ __align__(16) unsigned short Bs[3][4096];
    int t = threadIdx.x, lane = t & 63, wave = t >> 6;   // 8 waves
    int bi = blockIdx.x;
    int slot = bi >> 3;                // 0..293
    int q6 = slot / 6;
    int rr_ = (bi & 7) + 8 * q6;       // row-tile 0..391, xcd-grouped
    int cc_ = slot - 6 * q6;           // col-tile 0..5
    int col0 = cc_ * 128, row0 = rr_ * 128;
    int fr = lane & 15, fq = lane >> 4;
    int wm = (wave >> 2) * 64, wn = (wave & 3) * 32;
    int srow = lane >> 2;                                // staged row within wave's 16
    int sg = ((lane & 3) ^ ((lane >> 3) & 3)) * 16;      // pre-swizzled source chunk
    int rc = (fq ^ ((fr >> 1) & 3)) * 16;                // swizzled read chunk
    const char* Ab = (const char*)A;
    const char* Wb = (const char*)W;

    float4v acc[4][2] = {};

#define STAGE_BIG(buf, k0)                                                         \
    {                                                                              \
        gload_lds16(Ab + (size_t)(row0 + wave * 16 + srow) * 384 + (k0) * 2 + sg,  \
                    (char*)As[buf] + wave * 1024);                                 \
        gload_lds16(Wb + (size_t)(col0 + wave * 16 + srow) * 384 + (k0) * 2 + sg,  \
                    (char*)Bs[buf] + wave * 1024);                                 \
    }

    STAGE_BIG(0, 0);
    STAGE_BIG(1, 32);
#pragma unroll
    for (int s = 0; s < 6; ++s) {
        int buf = s % 3;
        if (s < 4) {
            STAGE_BIG((s + 2) % 3, (s + 2) * 32);
            asm volatile("s_waitcnt vmcnt(4)\n\ts_barrier" ::: "memory");
        } else if (s == 4) {
            asm volatile("s_waitcnt vmcnt(2)\n\ts_barrier" ::: "memory");
        } else {
            asm volatile("s_waitcnt vmcnt(0)\n\ts_barrier" ::: "memory");
        }
        short8 af[4], bf[2];
#pragma unroll
        for (int mi = 0; mi < 4; ++mi)
            af[mi] = *(const short8*)((const char*)As[buf] + (wm + mi * 16 + fr) * 64 + rc);
#pragma unroll
        for (int ni = 0; ni < 2; ++ni)
            bf[ni] = *(const short8*)((const char*)Bs[buf] + (wn + ni * 16 + fr) * 64 + rc);
        asm volatile("s_waitcnt lgkmcnt(0)\n\ts_barrier" ::: "memory");
        // SWAPPED: first operand = W-cols -> acc row index r spans output COLS,
        // lane&15 (fr) spans output rows (pos).
#pragma unroll
        for (int mi = 0; mi < 4; ++mi)
#pragma unroll
            for (int ni = 0; ni < 2; ++ni)
                acc[mi][ni] = __builtin_amdgcn_mfma_f32_16x16x32_bf16(
                    bf[ni], af[mi], acc[mi][ni], 0, 0, 0);
    }

    // epilogue: thread owns cols cb..cb+3 (cb = col0+wn+ni*16+fq*4, %4==0,
    // quarter-uniform) x pos = row0+wm+mi*16+fr.
#pragma unroll
    for (int ni = 0; ni < 2; ++ni) {
        int cb = col0 + wn + ni * 16 + fq * 4;
        float4v bb = *(const float4v*)(ball + cb);      // 16-B aligned (cb%4==0)
        if (cb < 192) {
            int hd = cb >> 5, ch = cb & 31;             // ch%4==0 -> 8-B aligned dst
            unsigned short* vp = Vo + (size_t)hd * NPOS * 32 + ch;
#pragma unroll
            for (int mi = 0; mi < 4; ++mi) {
                int pos = row0 + wm + mi * 16 + fr;
                uint2v pk;
                pk[0] = pack2bf(acc[mi][ni][0] + bb[0], acc[mi][ni][1] + bb[1]);
                pk[1] = pack2bf(acc[mi][ni][2] + bb[2], acc[mi][ni][3] + bb[3]);
                *(uint2v*)(vp + (size_t)pos * 32) = pk;
            }
        } else {
            int dp = cb - 192;
            int hd = dp / 96, rr2 = dp - hd * 96;
            int k9 = rr2 / 10, l = rr2 - k9 * 10;       // l in {0,2,4,6,8}
            if (k9 < 9) {
                unsigned short* rp  = ATo + ((size_t)(hd * 9 + k9) * NPOS) * 10 + l;
                unsigned short* rp2 = ATo + ((size_t)(hd * 9 + k9 + 1) * NPOS) * 10;
                bool full = (l <= 4);
                bool c6 = (l == 6);
                bool nx = (k9 + 1 < 9);
#pragma unroll
                for (int mi = 0; mi < 4; ++mi) {
                    int pos = row0 + wm + mi * 16 + fr;
                    unsigned short* q = rp + (size_t)pos * 10;   // dword-aligned (l even)
                    unsigned int lo = pack2bf(acc[mi][ni][0] + bb[0], acc[mi][ni][1] + bb[1]);
                    unsigned int hi = pack2bf(acc[mi][ni][2] + bb[2], acc[mi][ni][3] + bb[3]);
                    if (full) {
                        ((unsigned int*)q)[0] = lo;
                        ((unsigned int*)q)[1] = hi;
                    } else if (c6) {                     // l=6,7 pack; l=8 scalar; l=9 pad
                        ((unsigned int*)q)[0] = lo;
                        q[2] = f2bf(acc[mi][ni][2] + bb[2]);
                    } else {                             // l=8 scalar; l=9 pad; next record l=0,1
                        q[0] = f2bf(acc[mi][ni][0] + bb[0]);
                        if (nx) *(unsigned int*)(rp2 + (size_t)pos * 10) = hi;
                    }
                }
            }
        }
    }
#undef STAGE_BIG
}

// out[img][m][phw] = sum_k Wpt[m][k]*fold[n][k] + bias[m]; v12: 64(m) x 128(n)
// tile, grid 1176 (was 588 -> 2.3 blocks/CU, latency-starved). 4 waves each
// 64x32 (acc[4][2]). LDS 24 KB -> ~6 blocks/CU. XCD n-panel grouping:
// 1176 = 8*147; n-tile = (bi&7)+8*(slot/3), m-tile = slot%3 -> all 3 m-tiles
// of an n-panel on one XCD (fold-panel fetched once per L2).
__global__ __launch_bounds__(256, 4) void gemm_small(
    const unsigned short* __restrict__ A,   // Wpt [192][192]
    const unsigned short* __restrict__ B,   // fold [50176][192]
    const float* __restrict__ bias, float* __restrict__ out)
{
    __shared__ __align__(16) unsigned short As[2][2048];
    __shared__ __align__(16) unsigned short Bs[2][4096];
    int t = threadIdx.x, lane = t & 63, wave = t >> 6;
    int bi = blockIdx.x;
    int slot = bi >> 3;               // 0..146
    int q3 = slot / 3;                // 0..48
    int ntile = (bi & 7) + 8 * q3;    // 0..391
    int mtile = slot - 3 * q3;        // 0..2
    int n0 = ntile * 128, m0 = mtile * 64;
    int fr = lane & 15, fq = lane >> 4;
    int srow = lane >> 2;
    int sg = ((lane & 3) ^ ((lane >> 3) & 3)) * 16;      // pre-swizzled source chunk
    int rc = (fq ^ ((fr >> 1) & 3)) * 16;                // swizzled read chunk
    const char* Ab = (const char*)A;
    const char* Bb = (const char*)B;

    float4v acc[4][2] = {};

#define STAGE_SMALL(buf, k0)                                                       \
    {                                                                              \
        gload_lds16(Ab + (size_t)(m0 + wave * 16 + srow) * 384 + (k0)*2 + sg,      \
                    (char*)As[buf] + wave * 1024);                                 \
        gload_lds16(Bb + (size_t)(n0 + wave * 16 + srow) * 384 + (k0)*2 + sg,      \
                    (char*)Bs[buf] + wave * 1024);                                 \
        gload_lds16(Bb + (size_t)(n0 + 64 + wave * 16 + srow) * 384 + (k0)*2 + sg, \
                    (char*)Bs[buf] + 4096 + wave * 1024);                          \
    }

    STAGE_SMALL(0, 0);
    for (int s = 0; s < 6; ++s) {
        if (s < 5) {
            STAGE_SMALL((s + 1) & 1, (s + 1) * 32);
            asm volatile("s_waitcnt vmcnt(3)\n\ts_barrier" ::: "memory");
        } else {
            asm volatile("s_waitcnt vmcnt(0)\n\ts_barrier" ::: "memory");
        }
        int buf = s & 1;
        short8 af[4], bf[2];
#pragma unroll
        for (int mi = 0; mi < 4; ++mi)
            af[mi] = *(const short8*)((const char*)As[buf] + (mi * 16 + fr) * 64 + rc);
#pragma unroll
        for (int ni = 0; ni < 2; ++ni)
            bf[ni] = *(const short8*)((const char*)Bs[buf] + (wave * 32 + ni * 16 + fr) * 64 + rc);
        asm volatile("s_waitcnt lgkmcnt(0)\n\ts_barrier" ::: "memory");
#pragma unroll
        for (int mi = 0; mi < 4; ++mi)
#pragma unroll
            for (int ni = 0; ni < 2; ++ni)
                acc[mi][ni] = __builtin_amdgcn_mfma_f32_16x16x32_bf16(
                    af[mi], bf[ni], acc[mi][ni], 0, 0, 0);
    }

#pragma unroll
    for (int ni = 0; ni < 2; ++ni) {
        int n = n0 + wave * 32 + ni * 16 + fr;
        int img = n / HW, phw = n - img * HW;
        float* op = out + (size_t)img * (NC * HW) + phw;
#pragma unroll
        for (int mi = 0; mi < 4; ++mi) {
            int m = m0 + mi * 16 + fq * 4;
#pragma unroll
            for (int r = 0; r < 4; ++r)
                op[(size_t)(m + r) * HW] = acc[mi][ni][r] + bias[m + r];
        }
    }
#undef STAGE_SMALL
}

// Fused softmax + weight-combine + aggregation, v8: max load ILP.
// v7's stg[6] (48 VGPR) stayed live across the softmax under a 64-VGPR
// budget -> compiler serialized the 9 tap loads (~250 cyc L2 each). Now:
// issue V loads -> issue ALL 45 att dwords into ub[9][5] -> commit V to LDS
// -> barrier (drains everything once, overlapped) -> softmax from registers
// -> aggregate. launch_bounds(256,4) allows 128 VGPR.
__global__ __launch_bounds__(256, 4) void fused_att_agg(
    const unsigned short* __restrict__ V, const unsigned short* __restrict__ AT,
    unsigned short* __restrict__ fold)
{
    __shared__ __align__(16) char vt[4 * 434 * 16];   // 27776 B
    int t = threadIdx.x;
    int bid = blockIdx.x;
    int head = bid % NHEADS; int tmp = bid / NHEADS;
    int tcol = tmp & 1; tmp >>= 1;
    int trow = tmp % 7; int img = tmp / 7;
    int h0 = trow * 8, w0 = tcol * 28;

    // ---- issue v-halo loads into registers (clamped addr + zero mask) ----
    const unsigned short* Vh = V + (size_t)head * NPOS * 32;
    ushort8 stg[6];
#pragma unroll
    for (int i = 0; i < 6; ++i) {
        int u = i * 256 + t;                 // 0..1535
        int slot = u >> 2, q = u & 3;        // slot = vrow*32+vcol, q = 16-B quarter
        int vrow = slot >> 5, vcol = slot & 31;
        int hh = h0 - 2 + vrow, ww = w0 - 2 + vcol;
        bool ok = (hh >= 0) & (hh < IMG) & (ww >= 0) & (ww < IMG);
        int hc = min(max(hh, 0), IMG - 1);
        int wcl = min(max(ww, 0), IMG - 1);
        ushort8 val = *(const ushort8*)(Vh + (size_t)(img * HW + hc * IMG + wcl) * 32 + q * 8);
        if (!ok) val = (ushort8){};
        stg[i] = val;
    }

    // ---- issue ALL 9 taps' att loads (independent -> full ILP) ----
    int ph = t / 28, pw = t - (t / 28) * 28;
    int h = h0 + ph, w = w0 + pw;
    unsigned int ub[9][5];
    if (t < 224) {
        int head9 = head * 9;
#pragma unroll
        for (int k = 0; k < 9; ++k) {
            const int oky = k / 3 - 1, okx = k % 3 - 1;
            int hh = h - oky, ww = w - okx;
            int hc = min(max(hh, 0), IMG - 1);
            int wcl = min(max(ww, 0), IMG - 1);
            size_t nidx = (size_t)img * HW + hc * IMG + wcl;
            const unsigned int* ap32 =
                (const unsigned int*)(AT + ((size_t)(head9 + k) * NPOS + nidx) * 10);
#pragma unroll
            for (int z = 0; z < 5; ++z) ub[k][z] = ap32[z];
        }
    }

    // ---- commit staged halo to LDS (write-balanced: plane stride 2 mod 8) ----
#pragma unroll
    for (int i = 0; i < 6; ++i) {
        int u = i * 256 + t;
        int slot = u >> 2, q = u & 3;
        int vrow = slot >> 5, vcol = slot & 31;
        *(ushort8*)(vt + q * (434 * 16) + (vrow * 36 + vcol) * 16) = stg[i];
    }
    __syncthreads();

    // ---- softmax -> 5x5 stencil weights, from registers ----
    float wc[25];
#pragma unroll
    for (int d = 0; d < 25; ++d) wc[d] = 0.f;
    if (t < 224) {
#pragma unroll
        for (int k = 0; k < 9; ++k) {
            const int oky = k / 3 - 1, okx = k % 3 - 1;
            int hh = h - oky, ww = w - okx;
            bool ok = (hh >= 0) & (hh < IMG) & (ww >= 0) & (ww < IMG);
            float a[9] = { bf2f_lo(ub[k][0]), bf2f_hi(ub[k][0]),
                           bf2f_lo(ub[k][1]), bf2f_hi(ub[k][1]),
                           bf2f_lo(ub[k][2]), bf2f_hi(ub[k][2]),
                           bf2f_lo(ub[k][3]), bf2f_hi(ub[k][3]),
                           bf2f_lo(ub[k][4]) };
            float m = -1e30f;
#pragma unroll
            for (int l = 0; l < 9; ++l) m = fmaxf(m, a[l]);
            float s = 0.f;
#pragma unroll
            for (int l = 0; l < 9; ++l) {
                a[l] = __expf((a[l] - m) * ATT_SCALE);
                s += a[l];
            }
            float g = ok ? (1.f / s) : 0.f;   // invalid neighbor contributes 0
#pragma unroll
            for (int l = 0; l < 9; ++l) {
                const int dy = (l / 3 - 1) - oky + 2;
                const int dx = (l % 3 - 1) - okx + 2;
                wc[dy * 5 + dx] += a[l] * g;
            }
        }
    }

    // ---- aggregate: 25 taps x 4 quarters, read-balanced, imm offsets ----
    if (t < 224) {
        int base = (ph * 36 + pw) * 16;
        int pos = img * HW + h * IMG + w;
        unsigned short* fo = fold + (size_t)pos * NC + head * 32;
#pragma unroll
        for (int q = 0; q < 4; ++q) {
            const char* vq = vt + q * (434 * 16) + base;
            float acc[8];
#pragma unroll
            for (int j = 0; j < 8; ++j) acc[j] = 0.f;
#pragma unroll
            for (int d = 0; d < 25; ++d) {
                const int dy = d / 5, dx = d % 5;
                float wf = wc[d];
                uint4v vv = *(const uint4v*)(vq + (dy * 36 + dx) * 16);
#pragma unroll
                for (int z = 0; z < 4; ++z) {
                    acc[2 * z]     += wf * bf2f_lo(vv[z]);
                    acc[2 * z + 1] += wf * bf2f_hi(vv[z]);
                }
            }
            ushort8 ov;
#pragma unroll
            for (int j = 0; j < 8; ++j) ov[j] = f2bf(acc[j]);
            *(ushort8*)(fo + q * 8) = ov;
        }
    }
}

extern "C" void kernel_launch(void* const* d_in, const int* in_sizes, int n_in,
                              void* d_out, int out_size, void* d_ws, size_t ws_size,
                              hipStream_t stream)
{
    const float* x  = (const float*)d_in[0];
    const float* Wv = (const float*)d_in[1];
    const float* Wa = (const float*)d_in[2];
    const float* ba = (const float*)d_in[3];
    const float* Wp = (const float*)d_in[4];
    const float* bp = (const float*)d_in[5];
    float* out = (float*)d_out;

    unsigned short* xt   = (unsigned short*)d_ws;        // 9,633,792 (reused as fold)
    unsigned short* V    = xt + 9633792;                 // 9,633,792
    unsigned short* AT   = V + 9633792;                  // 27,095,040
    unsigned short* Wall = AT + 27095040;                // 147,456
    unsigned short* Wpt  = Wall + 147456;                // 36,864
    float*          ball = (float*)(Wpt + 36864);        // 768 floats
    unsigned short* foldb = xt;                          // xt dead after gemm_big

    dim3 blk(256);
    prep_weights<<<576, blk, 0, stream>>>(Wv, Wa, Wp, ba, Wall, Wpt, ball);
    transpose_x<<<dim3(784, 3), blk, 0, stream>>>(x, xt);
    gemm_big<<<2352, dim3(512), 0, stream>>>(xt, Wall, ball, V, AT);
    fused_att_agg<<<1344, blk, 0, stream>>>(V, AT, foldb);  // 16 img x 7 x 2 x 6 heads
    gemm_small<<<1176, blk, 0, stream>>>(Wpt, foldb, bp, out);
}

// Round 9
// 169.941 us; speedup vs baseline: 1.3132x; 1.0054x over previous
//
#include <hip/hip_runtime.h>
#include <hip/hip_bf16.h>
#include <math.h>

#define HW 3136
#define NPOS 50176          // 16 images x 3136
#define NC 192
#define NHEADS 6
#define IMG 56
#define NATT 486
#define ATT_SCALE 0.17677669529663687f  // 32^-0.5

typedef __attribute__((ext_vector_type(8))) short short8;
typedef __attribute__((ext_vector_type(8))) unsigned short ushort8;
typedef __attribute__((ext_vector_type(4))) float float4v;
typedef __attribute__((ext_vector_type(4))) unsigned int uint4v;
typedef __attribute__((ext_vector_type(2))) unsigned int uint2v;

__device__ __forceinline__ float bf2f(unsigned short u) {
    unsigned int x = ((unsigned int)u) << 16;
    return __builtin_bit_cast(float, x);
}
__device__ __forceinline__ float bf2f_lo(unsigned int u) {
    return __builtin_bit_cast(float, u << 16);
}
__device__ __forceinline__ float bf2f_hi(unsigned int u) {
    return __builtin_bit_cast(float, u & 0xffff0000u);
}
__device__ __forceinline__ unsigned short f2bf(float f) {
    __hip_bfloat16 h = __float2bfloat16(f);
    return __builtin_bit_cast(unsigned short, h);
}
__device__ __forceinline__ unsigned int pack2bf(float a, float b) {
    return (unsigned int)f2bf(a) | ((unsigned int)f2bf(b) << 16);
}
__device__ __forceinline__ void gload_lds16(const void* g, void* l) {
    __builtin_amdgcn_global_load_lds((const __attribute__((address_space(1))) void*)g,
                                     (__attribute__((address_space(3))) void*)l, 16, 0, 0);
}

// x [16][192][3136] fp32 -> xt [50176][192] bf16 (channels-last). grid (784,3), block 256.
__global__ __launch_bounds__(256) void transpose_x(const float* __restrict__ x,
                                                   unsigned short* __restrict__ xt)
{
    __shared__ float tile[64][65];
    int bx = blockIdx.x;
    int n = (bx * 64) / HW;
    int hw0 = (bx * 64) % HW;
    int c0 = blockIdx.y * 64;
    int tl = threadIdx.x & 63, tg = threadIdx.x >> 6;
    const float* xn = x + (size_t)n * NC * HW;
#pragma unroll
    for (int i = 0; i < 16; ++i)
        tile[tg * 16 + i][tl] = xn[(size_t)(c0 + tg * 16 + i) * HW + hw0 + tl];
    __syncthreads();
    unsigned short* xp = xt + ((size_t)n * HW + hw0) * NC + c0;
#pragma unroll
    for (int i = 0; i < 16; ++i) {
        int hwr = tg * 16 + i;
        xp[(size_t)hwr * NC + tl] = f2bf(tile[tl][hwr]);
    }
}

// Weight prep: Wall[768][192] = [Wv^T ; Wa^T permuted, stride 10], ball[768],
// Wpt[192][192] = Wp^T. grid 576, block 256.
__global__ __launch_bounds__(256) void prep_weights(
    const float* __restrict__ Wv, const float* __restrict__ Wa, const float* __restrict__ Wp,
    const float* __restrict__ ba,
    unsigned short* __restrict__ Wall, unsigned short* __restrict__ Wpt,
    float* __restrict__ ball)
{
    int idx = blockIdx.x * 256 + threadIdx.x;
    if (idx < 36864) {
        int d = idx / 192, k = idx - d * 192;
        Wpt[idx] = f2bf(Wp[(size_t)k * NC + d]);
    }
    if (idx < 147456) {                       // 768*192
        int d = idx / 192, k = idx - d * 192;
        unsigned short val;
        float bv = 0.f;
        if (d < 192) {
            val = f2bf(Wv[(size_t)k * NC + d]);
        } else {
            int dp = d - 192;                 // 0..575
            int head = dp / 96, rr = dp - head * 96;
            int k9 = rr / 10, l = rr - k9 * 10;
            bool valid = (k9 < 9) && (l < 9);
            int src = head * 81 + k9 * 9 + l;
            val = valid ? f2bf(Wa[(size_t)k * NATT + src]) : (unsigned short)0;
            bv = valid ? ba[src] : 0.f;
        }
        Wall[idx] = val;
        if (k == 0) ball[d] = bv;
    }
}

// GEMM over all 768 output cols; epilogue scatters into fused-friendly layouts:
//   cols [0,192)   -> V[head][pos][32]           (64-B records)
//   cols [192,768) -> AT[head*9+k9][pos][10]     (20-B records; k9==9 pads dropped)
// v13: 4-buffer, ONE barrier per K-step. With stage target (s+2)%4 and read
// s%4, buf B (read at iter B) is next overwritten at iter B+2's STAGE; to
// issue it a wave must pass iter B+1's barrier, which every wave reaches only
// after its own lgkmcnt(0) drained its iter-B reads -> the old second barrier
// is redundant. 12 -> 6 barriers/block. LDS 64 KB -> 2 blocks/CU (cross-block
// overlap covers barrier waits). Epilogue: operand-swapped MFMA (reg index =
// output cols) -> packed dword/dwordx2 stores. XOR swizzle: 0 bank conflicts.
// XCD row-grouping: all 6 col-blocks of row-tile r on XCD r%8.
// grid 2352 (1-D), block 512.
__global__ __launch_bounds__(512, 4) void gemm_big(
    const unsigned short* __restrict__ A, const unsigned short* __restrict__ W,
    const float* __restrict__ ball,
    unsigned short* __restrict__ Vo, unsigned short* __restrict__ ATo)
{
    __shared__ __align__(16) unsigned short As[4][4096];
    __shared__ __align__(16) unsigned short Bs[4][4096];
    int t = threadIdx.x, lane = t & 63, wave = t >> 6;   // 8 waves
    int bi = blockIdx.x;
    int slot = bi >> 3;                // 0..293
    int q6 = slot / 6;
    int rr_ = (bi & 7) + 8 * q6;       // row-tile 0..391, xcd-grouped
    int cc_ = slot - 6 * q6;           // col-tile 0..5
    int col0 = cc_ * 128, row0 = rr_ * 128;
    int fr = lane & 15, fq = lane >> 4;
    int wm = (wave >> 2) * 64, wn = (wave & 3) * 32;
    int srow = lane >> 2;                                // staged row within wave's 16
    int sg = ((lane & 3) ^ ((lane >> 3) & 3)) * 16;      // pre-swizzled source chunk
    int rc = (fq ^ ((fr >> 1) & 3)) * 16;                // swizzled read chunk
    const char* Ab = (const char*)A;
    const char* Wb = (const char*)W;

    float4v acc[4][2] = {};

#define STAGE_BIG(buf, k0)                                                         \
    {                                                                              \
        gload_lds16(Ab + (size_t)(row0 + wave * 16 + srow) * 384 + (k0) * 2 + sg,  \
                    (char*)As[buf] + wave * 1024);                                 \
        gload_lds16(Wb + (size_t)(col0 + wave * 16 + srow) * 384 + (k0) * 2 + sg,  \
                    (char*)Bs[buf] + wave * 1024);                                 \
    }

    STAGE_BIG(0, 0);
    STAGE_BIG(1, 32);
#pragma unroll
    for (int s = 0; s < 6; ++s) {
        int buf = s & 3;
        if (s < 4) {
            STAGE_BIG((s + 2) & 3, (s + 2) * 32);
            // buf s ready when only stages s+1,s+2 (4 loads) remain in flight
            asm volatile("s_waitcnt vmcnt(4)\n\ts_barrier" ::: "memory");
        } else if (s == 4) {
            asm volatile("s_waitcnt vmcnt(2)\n\ts_barrier" ::: "memory");
        } else {
            asm volatile("s_waitcnt vmcnt(0)\n\ts_barrier" ::: "memory");
        }
        short8 af[4], bf[2];
#pragma unroll
        for (int mi = 0; mi < 4; ++mi)
            af[mi] = *(const short8*)((const char*)As[buf] + (wm + mi * 16 + fr) * 64 + rc);
#pragma unroll
        for (int ni = 0; ni < 2; ++ni)
            bf[ni] = *(const short8*)((const char*)Bs[buf] + (wn + ni * 16 + fr) * 64 + rc);
        // per-wave drain only: 4-buf distance makes the cross-wave overwrite
        // hazard impossible before the NEXT barrier (see header comment)
        asm volatile("s_waitcnt lgkmcnt(0)" ::: "memory");
        __builtin_amdgcn_sched_barrier(0);   // keep MFMA below the lgkm drain
        // SWAPPED: first operand = W-cols -> acc reg index spans output COLS,
        // lane&15 (fr) spans output rows (pos).
#pragma unroll
        for (int mi = 0; mi < 4; ++mi)
#pragma unroll
            for (int ni = 0; ni < 2; ++ni)
                acc[mi][ni] = __builtin_amdgcn_mfma_f32_16x16x32_bf16(
                    bf[ni], af[mi], acc[mi][ni], 0, 0, 0);
    }

    // epilogue: thread owns cols cb..cb+3 (cb = col0+wn+ni*16+fq*4, %4==0,
    // quarter-uniform) x pos = row0+wm+mi*16+fr.
#pragma unroll
    for (int ni = 0; ni < 2; ++ni) {
        int cb = col0 + wn + ni * 16 + fq * 4;
        float4v bb = *(const float4v*)(ball + cb);      // 16-B aligned (cb%4==0)
        if (cb < 192) {
            int hd = cb >> 5, ch = cb & 31;             // ch%4==0 -> 8-B aligned dst
            unsigned short* vp = Vo + (size_t)hd * NPOS * 32 + ch;
#pragma unroll
            for (int mi = 0; mi < 4; ++mi) {
                int pos = row0 + wm + mi * 16 + fr;
                uint2v pk;
                pk[0] = pack2bf(acc[mi][ni][0] + bb[0], acc[mi][ni][1] + bb[1]);
                pk[1] = pack2bf(acc[mi][ni][2] + bb[2], acc[mi][ni][3] + bb[3]);
                *(uint2v*)(vp + (size_t)pos * 32) = pk;
            }
        } else {
            int dp = cb - 192;
            int hd = dp / 96, rr2 = dp - hd * 96;
            int k9 = rr2 / 10, l = rr2 - k9 * 10;       // l in {0,2,4,6,8}
            if (k9 < 9) {
                unsigned short* rp  = ATo + ((size_t)(hd * 9 + k9) * NPOS) * 10 + l;
                unsigned short* rp2 = ATo + ((size_t)(hd * 9 + k9 + 1) * NPOS) * 10;
                bool full = (l <= 4);
                bool c6 = (l == 6);
                bool nx = (k9 + 1 < 9);
#pragma unroll
                for (int mi = 0; mi < 4; ++mi) {
                    int pos = row0 + wm + mi * 16 + fr;
                    unsigned short* q = rp + (size_t)pos * 10;   // dword-aligned (l even)
                    unsigned int lo = pack2bf(acc[mi][ni][0] + bb[0], acc[mi][ni][1] + bb[1]);
                    unsigned int hi = pack2bf(acc[mi][ni][2] + bb[2], acc[mi][ni][3] + bb[3]);
                    if (full) {
                        ((unsigned int*)q)[0] = lo;
                        ((unsigned int*)q)[1] = hi;
                    } else if (c6) {                     // l=6,7 pack; l=8 scalar; l=9 pad
                        ((unsigned int*)q)[0] = lo;
                        q[2] = f2bf(acc[mi][ni][2] + bb[2]);
                    } else {                             // l=8 scalar; l=9 pad; next record l=0,1
                        q[0] = f2bf(acc[mi][ni][0] + bb[0]);
                        if (nx) *(unsigned int*)(rp2 + (size_t)pos * 10) = hi;
                    }
                }
            }
        }
    }
#undef STAGE_BIG
}

// out[img][m][phw] = sum_k Wpt[m][k]*fold[n][k] + bias[m]; v12: 64(m) x 128(n)
// tile, grid 1176. 4 waves each 64x32 (acc[4][2]). LDS 24 KB -> ~6 blocks/CU.
// XCD n-panel grouping: 1176 = 8*147; all 3 m-tiles of an n-panel on one XCD.
__global__ __launch_bounds__(256, 4) void gemm_small(
    const unsigned short* __restrict__ A,   // Wpt [192][192]
    const unsigned short* __restrict__ B,   // fold [50176][192]
    const float* __restrict__ bias, float* __restrict__ out)
{
    __shared__ __align__(16) unsigned short As[2][2048];
    __shared__ __align__(16) unsigned short Bs[2][4096];
    int t = threadIdx.x, lane = t & 63, wave = t >> 6;
    int bi = blockIdx.x;
    int slot = bi >> 3;               // 0..146
    int q3 = slot / 3;                // 0..48
    int ntile = (bi & 7) + 8 * q3;    // 0..391
    int mtile = slot - 3 * q3;        // 0..2
    int n0 = ntile * 128, m0 = mtile * 64;
    int fr = lane & 15, fq = lane >> 4;
    int srow = lane >> 2;
    int sg = ((lane & 3) ^ ((lane >> 3) & 3)) * 16;      // pre-swizzled source chunk
    int rc = (fq ^ ((fr >> 1) & 3)) * 16;                // swizzled read chunk
    const char* Ab = (const char*)A;
    const char* Bb = (const char*)B;

    float4v acc[4][2] = {};

#define STAGE_SMALL(buf, k0)                                                       \
    {                                                                              \
        gload_lds16(Ab + (size_t)(m0 + wave * 16 + srow) * 384 + (k0)*2 + sg,      \
                    (char*)As[buf] + wave * 1024);                                 \
        gload_lds16(Bb + (size_t)(n0 + wave * 16 + srow) * 384 + (k0)*2 + sg,      \
                    (char*)Bs[buf] + wave * 1024);                                 \
        gload_lds16(Bb + (size_t)(n0 + 64 + wave * 16 + srow) * 384 + (k0)*2 + sg, \
                    (char*)Bs[buf] + 4096 + wave * 1024);                          \
    }

    STAGE_SMALL(0, 0);
    for (int s = 0; s < 6; ++s) {
        if (s < 5) {
            STAGE_SMALL((s + 1) & 1, (s + 1) * 32);
            asm volatile("s_waitcnt vmcnt(3)\n\ts_barrier" ::: "memory");
        } else {
            asm volatile("s_waitcnt vmcnt(0)\n\ts_barrier" ::: "memory");
        }
        int buf = s & 1;
        short8 af[4], bf[2];
#pragma unroll
        for (int mi = 0; mi < 4; ++mi)
            af[mi] = *(const short8*)((const char*)As[buf] + (mi * 16 + fr) * 64 + rc);
#pragma unroll
        for (int ni = 0; ni < 2; ++ni)
            bf[ni] = *(const short8*)((const char*)Bs[buf] + (wave * 32 + ni * 16 + fr) * 64 + rc);
        asm volatile("s_waitcnt lgkmcnt(0)\n\ts_barrier" ::: "memory");
#pragma unroll
        for (int mi = 0; mi < 4; ++mi)
#pragma unroll
            for (int ni = 0; ni < 2; ++ni)
                acc[mi][ni] = __builtin_amdgcn_mfma_f32_16x16x32_bf16(
                    af[mi], bf[ni], acc[mi][ni], 0, 0, 0);
    }

#pragma unroll
    for (int ni = 0; ni < 2; ++ni) {
        int n = n0 + wave * 32 + ni * 16 + fr;
        int img = n / HW, phw = n - img * HW;
        float* op = out + (size_t)img * (NC * HW) + phw;
#pragma unroll
        for (int mi = 0; mi < 4; ++mi) {
            int m = m0 + mi * 16 + fq * 4;
#pragma unroll
            for (int r = 0; r < 4; ++r)
                op[(size_t)(m + r) * HW] = acc[mi][ni][r] + bias[m + r];
        }
    }
#undef STAGE_SMALL
}

// Fused softmax + weight-combine + aggregation, v8: max load ILP.
// issue V loads -> issue ALL 45 att dwords into ub[9][5] -> commit V to LDS
// -> barrier (drains everything once, overlapped) -> softmax from registers
// -> aggregate. launch_bounds(256,4) allows 128 VGPR.
__global__ __launch_bounds__(256, 4) void fused_att_agg(
    const unsigned short* __restrict__ V, const unsigned short* __restrict__ AT,
    unsigned short* __restrict__ fold)
{
    __shared__ __align__(16) char vt[4 * 434 * 16];   // 27776 B
    int t = threadIdx.x;
    int bid = blockIdx.x;
    int head = bid % NHEADS; int tmp = bid / NHEADS;
    int tcol = tmp & 1; tmp >>= 1;
    int trow = tmp % 7; int img = tmp / 7;
    int h0 = trow * 8, w0 = tcol * 28;

    // ---- issue v-halo loads into registers (clamped addr + zero mask) ----
    const unsigned short* Vh = V + (size_t)head * NPOS * 32;
    ushort8 stg[6];
#pragma unroll
    for (int i = 0; i < 6; ++i) {
        int u = i * 256 + t;                 // 0..1535
        int slot = u >> 2, q = u & 3;        // slot = vrow*32+vcol, q = 16-B quarter
        int vrow = slot >> 5, vcol = slot & 31;
        int hh = h0 - 2 + vrow, ww = w0 - 2 + vcol;
        bool ok = (hh >= 0) & (hh < IMG) & (ww >= 0) & (ww < IMG);
        int hc = min(max(hh, 0), IMG - 1);
        int wcl = min(max(ww, 0), IMG - 1);
        ushort8 val = *(const ushort8*)(Vh + (size_t)(img * HW + hc * IMG + wcl) * 32 + q * 8);
        if (!ok) val = (ushort8){};
        stg[i] = val;
    }

    // ---- issue ALL 9 taps' att loads (independent -> full ILP) ----
    int ph = t / 28, pw = t - (t / 28) * 28;
    int h = h0 + ph, w = w0 + pw;
    unsigned int ub[9][5];
    if (t < 224) {
        int head9 = head * 9;
#pragma unroll
        for (int k = 0; k < 9; ++k) {
            const int oky = k / 3 - 1, okx = k % 3 - 1;
            int hh = h - oky, ww = w - okx;
            int hc = min(max(hh, 0), IMG - 1);
            int wcl = min(max(ww, 0), IMG - 1);
            size_t nidx = (size_t)img * HW + hc * IMG + wcl;
            const unsigned int* ap32 =
                (const unsigned int*)(AT + ((size_t)(head9 + k) * NPOS + nidx) * 10);
#pragma unroll
            for (int z = 0; z < 5; ++z) ub[k][z] = ap32[z];
        }
    }

    // ---- commit staged halo to LDS (write-balanced: plane stride 2 mod 8) ----
#pragma unroll
    for (int i = 0; i < 6; ++i) {
        int u = i * 256 + t;
        int slot = u >> 2, q = u & 3;
        int vrow = slot >> 5, vcol = slot & 31;
        *(ushort8*)(vt + q * (434 * 16) + (vrow * 36 + vcol) * 16) = stg[i];
    }
    __syncthreads();

    // ---- softmax -> 5x5 stencil weights, from registers ----
    float wc[25];
#pragma unroll
    for (int d = 0; d < 25; ++d) wc[d] = 0.f;
    if (t < 224) {
#pragma unroll
        for (int k = 0; k < 9; ++k) {
            const int oky = k / 3 - 1, okx = k % 3 - 1;
            int hh = h - oky, ww = w - okx;
            bool ok = (hh >= 0) & (hh < IMG) & (ww >= 0) & (ww < IMG);
            float a[9] = { bf2f_lo(ub[k][0]), bf2f_hi(ub[k][0]),
                           bf2f_lo(ub[k][1]), bf2f_hi(ub[k][1]),
                           bf2f_lo(ub[k][2]), bf2f_hi(ub[k][2]),
                           bf2f_lo(ub[k][3]), bf2f_hi(ub[k][3]),
                           bf2f_lo(ub[k][4]) };
            float m = -1e30f;
#pragma unroll
            for (int l = 0; l < 9; ++l) m = fmaxf(m, a[l]);
            float s = 0.f;
#pragma unroll
            for (int l = 0; l < 9; ++l) {
                a[l] = __expf((a[l] - m) * ATT_SCALE);
                s += a[l];
            }
            float g = ok ? (1.f / s) : 0.f;   // invalid neighbor contributes 0
#pragma unroll
            for (int l = 0; l < 9; ++l) {
                const int dy = (l / 3 - 1) - oky + 2;
                const int dx = (l % 3 - 1) - okx + 2;
                wc[dy * 5 + dx] += a[l] * g;
            }
        }
    }

    // ---- aggregate: 25 taps x 4 quarters, read-balanced, imm offsets ----
    if (t < 224) {
        int base = (ph * 36 + pw) * 16;
        int pos = img * HW + h * IMG + w;
        unsigned short* fo = fold + (size_t)pos * NC + head * 32;
#pragma unroll
        for (int q = 0; q < 4; ++q) {
            const char* vq = vt + q * (434 * 16) + base;
            float acc[8];
#pragma unroll
            for (int j = 0; j < 8; ++j) acc[j] = 0.f;
#pragma unroll
            for (int d = 0; d < 25; ++d) {
                const int dy = d / 5, dx = d % 5;
                float wf = wc[d];
                uint4v vv = *(const uint4v*)(vq + (dy * 36 + dx) * 16);
#pragma unroll
                for (int z = 0; z < 4; ++z) {
                    acc[2 * z]     += wf * bf2f_lo(vv[z]);
                    acc[2 * z + 1] += wf * bf2f_hi(vv[z]);
                }
            }
            ushort8 ov;
#pragma unroll
            for (int j = 0; j < 8; ++j) ov[j] = f2bf(acc[j]);
            *(ushort8*)(fo + q * 8) = ov;
        }
    }
}

extern "C" void kernel_launch(void* const* d_in, const int* in_sizes, int n_in,
                              void* d_out, int out_size, void* d_ws, size_t ws_size,
                              hipStream_t stream)
{
    const float* x  = (const float*)d_in[0];
    const float* Wv = (const float*)d_in[1];
    const float* Wa = (const float*)d_in[2];
    const float* ba = (const float*)d_in[3];
    const float* Wp = (const float*)d_in[4];
    const float* bp = (const float*)d_in[5];
    float* out = (float*)d_out;

    unsigned short* xt   = (unsigned short*)d_ws;        // 9,633,792 (reused as fold)
    unsigned short* V    = xt + 9633792;                 // 9,633,792
    unsigned short* AT   = V + 9633792;                  // 27,095,040
    unsigned short* Wall = AT + 27095040;                // 147,456
    unsigned short* Wpt  = Wall + 147456;                // 36,864
    float*          ball = (float*)(Wpt + 36864);        // 768 floats
    unsigned short* foldb = xt;                          // xt dead after gemm_big

    dim3 blk(256);
    prep_weights<<<576, blk, 0, stream>>>(Wv, Wa, Wp, ba, Wall, Wpt, ball);
    transpose_x<<<dim3(784, 3), blk, 0, stream>>>(x, xt);
    gemm_big<<<2352, dim3(512), 0, stream>>>(xt, Wall, ball, V, AT);
    fused_att_agg<<<1344, blk, 0, stream>>>(V, AT, foldb);  // 16 img x 7 x 2 x 6 heads
    gemm_small<<<1176, blk, 0, stream>>>(Wpt, foldb, bp, out);
}